// Round 6
// baseline (451.446 us; speedup 1.0000x reference)
//
#include <hip/hip_runtime.h>
#include <stdint.h>

#define S_LEN 2048
#define D_DIM 7168
#define H_NUM 64
#define HD_DIM 128
#define QLR_DIM 1536
#define NQ_DIM 8192      // H*HD
#define ROPE_DIM 64
#define HALF_DIM 32
#define TOPK_N 512
#define NEG_INF_F (-1e30f)
#define LN_EPS 1e-6f
#define W_SCALE 0.011048543456039806f   // 1/sqrt(64*128)

#define KCHUNKS 7
#define KCHUNK_SZ 1024

// workspace layout (float offsets)
#define QBF_OFF 0                                    // S*NQ bf16 = 8388608 floats
#define ALORA_OFF (QBF_OFF + S_LEN * NQ_DIM / 2)     // q_lora bf16
#define WT_OFF   (ALORA_OFF + S_LEN * QLR_DIM / 2)   // wq_b^T bf16
#define XBF_OFF  (WT_OFF + NQ_DIM * QLR_DIM / 2)     // x bf16: S*D/2 floats
#define WT2_OFF  (XBF_OFF + S_LEN * D_DIM / 2)       // [wk|wproj]^T bf16: 192*D/2
#define KF_OFF   (WT2_OFF + 192 * D_DIM / 2)
#define KBF_OFF  (KF_OFF + S_LEN * HD_DIM)
#define WF_OFF   (KBF_OFF + S_LEN * HD_DIM / 2)
#define SC_OFF   (WF_OFF + S_LEN * H_NUM)            // scores S*S fp32
// split-K partials (7*S*192 = 2.75M floats) alias the score region (4.19M)

typedef __attribute__((ext_vector_type(8))) short short8;
typedef __attribute__((ext_vector_type(4))) float floatx4;

__device__ __forceinline__ ushort f2bf(float f) {
    unsigned int u = __float_as_uint(f);
    u += 0x7FFFu + ((u >> 16) & 1u);   // round-to-nearest-even
    return (ushort)(u >> 16);
}
__device__ __forceinline__ unsigned int pack2bf(float lo, float hi) {
    return (unsigned int)f2bf(lo) | ((unsigned int)f2bf(hi) << 16);
}

__device__ __forceinline__ void gld_lds16(const ushort* g, ushort* l) {
    __builtin_amdgcn_global_load_lds(
        (const __attribute__((address_space(1))) unsigned int*)g,
        (__attribute__((address_space(3))) unsigned int*)l, 16, 0, 0);
}

// ---------------------------------------------------------------------------
// Kernel 0a: generic fp32 -> bf16 cast (8 elems/thread)
// ---------------------------------------------------------------------------
__global__ __launch_bounds__(256) void cast_bf16_kernel(
    const float* __restrict__ in, ushort* __restrict__ out)
{
    int g = (blockIdx.x * 256 + threadIdx.x) * 8;
    float4 a = *(const float4*)&in[g];
    float4 b = *(const float4*)&in[g + 4];
    uint4 v;
    v.x = pack2bf(a.x, a.y); v.y = pack2bf(a.z, a.w);
    v.z = pack2bf(b.x, b.y); v.w = pack2bf(b.z, b.w);
    *(uint4*)&out[g] = v;
}

// ---------------------------------------------------------------------------
// Kernel 0b: transpose+cast wq_b fp32 [QLR][NQ] -> bf16 WT [NQ][QLR].
// ---------------------------------------------------------------------------
__global__ __launch_bounds__(256) void transpose_wqb_kernel(
    const float* __restrict__ W, ushort* __restrict__ WT)
{
    __shared__ ushort tl[64][72];
    const int n0 = blockIdx.x * 64, k0 = blockIdx.y * 64;
    const int t = threadIdx.x;
    const int r = t >> 4, c4 = (t & 15) * 4;
#pragma unroll
    for (int u = 0; u < 4; u++) {
        int kk = r + u * 16;
        float4 v = *(const float4*)&W[(size_t)(k0 + kk) * NQ_DIM + n0 + c4];
        tl[c4 + 0][kk] = f2bf(v.x);
        tl[c4 + 1][kk] = f2bf(v.y);
        tl[c4 + 2][kk] = f2bf(v.z);
        tl[c4 + 3][kk] = f2bf(v.w);
    }
    __syncthreads();
#pragma unroll
    for (int u = 0; u < 2; u++) {
        int i = t + u * 256;             // 512 chunks of 16B
        int nr = i >> 3, c8 = (i & 7) * 8;
        uint4 v = *(const uint4*)&tl[nr][c8];
        *(uint4*)&WT[(size_t)(n0 + nr) * QLR_DIM + k0 + c8] = v;
    }
}

// ---------------------------------------------------------------------------
// Kernel 0c: transpose+cast [wk | wproj] -> bf16 WT2 [192][D].
// ---------------------------------------------------------------------------
__global__ __launch_bounds__(256) void transpose_wkp_kernel(
    const float* __restrict__ WK, const float* __restrict__ WP,
    ushort* __restrict__ WT2)
{
    __shared__ ushort tl[64][72];
    const int ntile = blockIdx.x;
    const int k0 = blockIdx.y * 64;
    const float* src; int ld, cbase;
    if (ntile < 2) { src = WK; ld = HD_DIM; cbase = ntile * 64; }
    else           { src = WP; ld = H_NUM; cbase = 0; }
    const int t = threadIdx.x;
    const int r = t >> 4, c4 = (t & 15) * 4;
#pragma unroll
    for (int u = 0; u < 4; u++) {
        int kk = r + u * 16;
        float4 v = *(const float4*)&src[(size_t)(k0 + kk) * ld + cbase + c4];
        tl[c4 + 0][kk] = f2bf(v.x);
        tl[c4 + 1][kk] = f2bf(v.y);
        tl[c4 + 2][kk] = f2bf(v.z);
        tl[c4 + 3][kk] = f2bf(v.w);
    }
    __syncthreads();
#pragma unroll
    for (int u = 0; u < 2; u++) {
        int i = t + u * 256;
        int nr = i >> 3, c8 = (i & 7) * 8;
        uint4 v = *(const uint4*)&tl[nr][c8];
        *(uint4*)&WT2[(size_t)(ntile * 64 + nr) * D_DIM + k0 + c8] = v;
    }
}

// ---------------------------------------------------------------------------
// Kernel 1: Q = q_lora @ wq_b via bf16 MFMA (m97 structure). Fused RoPE
// epilogue, LDS-bounced coalesced store to [H][S][HD].
// ---------------------------------------------------------------------------
__global__ __launch_bounds__(256) void qgemm_mfma_kernel(
    const ushort* __restrict__ Abf,   // bf16 [S][QLR]
    const ushort* __restrict__ WT,    // bf16 [NQ][QLR]
    const float* __restrict__ cosp, const float* __restrict__ sinp,
    ushort* __restrict__ Qo)          // bf16 [H][S][HD]
{
    __shared__ ushort lds[128 * 136];          // staging aliases front
    ushort* As = lds;                          // 128 rows x 32 bf16
    ushort* Bs = lds + 4096;

    const int tid = threadIdx.x;
    const int lane = tid & 63;
    const int wave = tid >> 6;
    const int m = lane & 15;
    const int q = lane >> 4;
    const int wm = wave & 1, wn = wave >> 1;
    const int m0 = blockIdx.y * 128;
    const int n0 = blockIdx.x * 128;
    const int h = blockIdx.x;

    floatx4 acc[4][4];
#pragma unroll
    for (int i = 0; i < 4; i++)
#pragma unroll
        for (int j = 0; j < 4; j++) acc[i][j] = (floatx4){0.f, 0.f, 0.f, 0.f};

    const ushort* agp[2];
    const ushort* bgp[2];
    unsigned int sbase[2];
#pragma unroll
    for (int u = 0; u < 2; u++) {
        int s = (u * 4 + wave) * 64 + lane;
        agp[u] = Abf + (size_t)(m0 + (s >> 2)) * QLR_DIM + (s & 3) * 8;
        bgp[u] = WT + (size_t)(n0 + (s >> 2)) * QLR_DIM + (s & 3) * 8;
        sbase[u] = (unsigned int)((u * 4 + wave) * 64 * 8);
    }

    for (int kt = 0; kt < QLR_DIM; kt += 32) {
        __syncthreads();
#pragma unroll
        for (int u = 0; u < 2; u++) gld_lds16(agp[u] + kt, &As[sbase[u]]);
#pragma unroll
        for (int u = 0; u < 2; u++) gld_lds16(bgp[u] + kt, &Bs[sbase[u]]);
        __syncthreads();

        short8 af[4], bf[4];
#pragma unroll
        for (int mt = 0; mt < 4; mt++)
            af[mt] = *(const short8*)&As[(wm * 64 + mt * 16 + m) * 32 + q * 8];
#pragma unroll
        for (int nt = 0; nt < 4; nt++)
            bf[nt] = *(const short8*)&Bs[(wn * 64 + nt * 16 + m) * 32 + q * 8];
#pragma unroll
        for (int mt = 0; mt < 4; mt++)
#pragma unroll
            for (int nt = 0; nt < 4; nt++)
                acc[mt][nt] = __builtin_amdgcn_mfma_f32_16x16x32_bf16(
                    af[mt], bf[nt], acc[mt][nt], 0, 0, 0);
    }

    __syncthreads();
    ushort* ep = lds;  // 128 x (pitch 136) bf16

#pragma unroll
    for (int mt = 0; mt < 4; mt++) {
        const int srow_base = m0 + wm * 64 + mt * 16 + q * 4;
#pragma unroll
        for (int nt = 0; nt < 4; nt++) {
            const int d = wn * 64 + nt * 16 + m;
            float o[4];
            if (wn == 0) {          // d < 64 -> rope
                const int jj = d >> 1;
#pragma unroll
                for (int r = 0; r < 4; r++) {
                    float x = acc[mt][nt][r];
                    float p = __shfl_xor(x, 1, 64);
                    float c = cosp[(srow_base + r) * HALF_DIM + jj];
                    float sn = sinp[(srow_base + r) * HALF_DIM + jj];
                    o[r] = (d & 1) ? (p * sn + x * c) : (x * c - p * sn);
                }
            } else {
#pragma unroll
                for (int r = 0; r < 4; r++) o[r] = acc[mt][nt][r];
            }
#pragma unroll
            for (int r = 0; r < 4; r++)
                ep[(wm * 64 + mt * 16 + q * 4 + r) * 136 + d] = f2bf(o[r]);
        }
    }
    __syncthreads();

#pragma unroll
    for (int u = 0; u < 8; u++) {
        int i = tid + u * 256;
        int row = i >> 4, c8 = (i & 15) * 8;
        uint4 v = *(const uint4*)&ep[row * 136 + c8];
        *(uint4*)&Qo[((size_t)h * S_LEN + m0 + row) * HD_DIM + c8] = v;
    }
}

// ---------------------------------------------------------------------------
// Kernel 2: [ktmp|w] = x @ [wk|wproj] via bf16 MFMA, split-K. grid (16,3,7).
// ---------------------------------------------------------------------------
__global__ __launch_bounds__(256) void kw_mfma_kernel(
    const ushort* __restrict__ Xbf,   // bf16 [S][D]
    const ushort* __restrict__ WT2,   // bf16 [192][D]
    float* __restrict__ partial)      // [kc][S][192]
{
    __shared__ ushort As[128 * 64];   // 16 KB
    __shared__ ushort Bs[64 * 64];    //  8 KB

    const int tid = threadIdx.x;
    const int lane = tid & 63;
    const int wave = tid >> 6;
    const int m = lane & 15;
    const int q = lane >> 4;
    const int wm = wave & 1, wn = wave >> 1;
    const int m0 = blockIdx.x * 128;
    const int n0 = blockIdx.y * 64;
    const int kc = blockIdx.z;
    const size_t kbase = (size_t)kc * KCHUNK_SZ;

    const ushort* agp[4];
    unsigned int abase[4];
#pragma unroll
    for (int u = 0; u < 4; u++) {
        int s = (u * 4 + wave) * 64 + lane;
        int row = s >> 3, c = s & 7;
        int kg = c ^ (row & 7);
        agp[u] = Xbf + (size_t)(m0 + row) * D_DIM + kbase + kg * 8;
        abase[u] = (unsigned int)((u * 4 + wave) * 64 * 8);
    }
    const ushort* bgp[2];
    unsigned int bbase[2];
#pragma unroll
    for (int u = 0; u < 2; u++) {
        int s = (u * 4 + wave) * 64 + lane;
        int row = s >> 3, c = s & 7;
        int kg = c ^ (row & 7);
        bgp[u] = WT2 + (size_t)(n0 + row) * D_DIM + kbase + kg * 8;
        bbase[u] = (unsigned int)((u * 4 + wave) * 64 * 8);
    }

    floatx4 acc[4][2];
#pragma unroll
    for (int i = 0; i < 4; i++)
#pragma unroll
        for (int j = 0; j < 2; j++) acc[i][j] = (floatx4){0.f, 0.f, 0.f, 0.f};

    for (int kt = 0; kt < KCHUNK_SZ; kt += 64) {
        __syncthreads();
#pragma unroll
        for (int u = 0; u < 4; u++) gld_lds16(agp[u] + kt, &As[abase[u]]);
#pragma unroll
        for (int u = 0; u < 2; u++) gld_lds16(bgp[u] + kt, &Bs[bbase[u]]);
        __syncthreads();

        short8 af[4][2], bfr[2][2];
#pragma unroll
        for (int mt = 0; mt < 4; mt++) {
            int row = wm * 64 + mt * 16 + m;
#pragma unroll
            for (int ks = 0; ks < 2; ks++)
                af[mt][ks] = *(const short8*)
                    &As[row * 64 + ((((ks << 2) + q) ^ (m & 7)) * 8)];
        }
#pragma unroll
        for (int nt = 0; nt < 2; nt++) {
            int row = wn * 32 + nt * 16 + m;
#pragma unroll
            for (int ks = 0; ks < 2; ks++)
                bfr[nt][ks] = *(const short8*)
                    &Bs[row * 64 + ((((ks << 2) + q) ^ (m & 7)) * 8)];
        }
#pragma unroll
        for (int mt = 0; mt < 4; mt++)
#pragma unroll
            for (int nt = 0; nt < 2; nt++)
#pragma unroll
                for (int ks = 0; ks < 2; ks++)
                    acc[mt][nt] = __builtin_amdgcn_mfma_f32_16x16x32_bf16(
                        af[mt][ks], bfr[nt][ks], acc[mt][nt], 0, 0, 0);
    }

#pragma unroll
    for (int mt = 0; mt < 4; mt++) {
        int grow = m0 + wm * 64 + mt * 16 + q * 4;
#pragma unroll
        for (int nt = 0; nt < 2; nt++) {
            int gn = n0 + wn * 32 + nt * 16 + m;
#pragma unroll
            for (int r = 0; r < 4; r++)
                partial[((size_t)kc * S_LEN + grow + r) * 192 + gn] = acc[mt][nt][r];
        }
    }
}

__global__ __launch_bounds__(256) void kw_reduce_kernel(
    const float* __restrict__ partial, float* __restrict__ Ko, float* __restrict__ Wo)
{
    int g = blockIdx.x * 256 + threadIdx.x;   // < S*192
    int m = g / 192, n = g % 192;
    float s = 0.f;
#pragma unroll
    for (int c = 0; c < KCHUNKS; c++)
        s += partial[((size_t)c * S_LEN + m) * 192 + n];
    if (n < HD_DIM) Ko[(size_t)m * HD_DIM + n] = s;
    else            Wo[(size_t)m * H_NUM + (n - HD_DIM)] = s * W_SCALE;
}

// ---------------------------------------------------------------------------
// Kernel 3: per-row layernorm + interleaved RoPE on k; emits bf16 K.
// ---------------------------------------------------------------------------
__global__ __launch_bounds__(128) void knorm_rope_kernel(
    const float* __restrict__ Kf, const float* __restrict__ gw, const float* __restrict__ gb,
    const float* __restrict__ cosp, const float* __restrict__ sinp,
    ushort* __restrict__ Kbf)
{
    __shared__ float red[128];
    __shared__ float sh[128];
    const int m = blockIdx.x, t = threadIdx.x;
    float v = Kf[(size_t)m * HD_DIM + t];
    red[t] = v; __syncthreads();
    for (int off = 64; off > 0; off >>= 1) {
        if (t < off) red[t] += red[t + off];
        __syncthreads();
    }
    float mu = red[0] * (1.f / HD_DIM);
    __syncthreads();
    float dv = v - mu;
    red[t] = dv * dv; __syncthreads();
    for (int off = 64; off > 0; off >>= 1) {
        if (t < off) red[t] += red[t + off];
        __syncthreads();
    }
    float var = red[0] * (1.f / HD_DIM);
    float rs = rsqrtf(var + LN_EPS);
    float kn = dv * rs * gw[t] + gb[t];
    sh[t] = kn; __syncthreads();
    float out;
    if (t < ROPE_DIM) {
        int jj = t >> 1;
        float c = cosp[m * HALF_DIM + jj], sn = sinp[m * HALF_DIM + jj];
        out = ((t & 1) == 0) ? (sh[t] * c - sh[t + 1] * sn)
                             : (sh[t - 1] * sn + sh[t] * c);
    } else {
        out = kn;
    }
    Kbf[(size_t)m * HD_DIM + t] = f2bf(out);
}

// ---------------------------------------------------------------------------
// Kernel 4: index_score via bf16 MFMA, barrier-free head loop.
// XCD-aware tile map: XCD x (= bidx%8, round-robin dispatch) owns ts groups
// {x, 31-x, x+8, 23-x} = 66 tiles each (exact balance). All readers of a
// ts group run consecutively on one XCD -> Q slice stays L2-resident.
// Depth-4 rotating register prefetch of Q A-fragments hides L2 latency.
// ---------------------------------------------------------------------------
__global__ __launch_bounds__(256) void attn_mfma_kernel(
    const ushort* __restrict__ Qb,  // bf16 [H][S][HD]
    const ushort* __restrict__ Kb,  // bf16 [S][HD]
    const float* __restrict__ Wf,   // fp32 [S][H], pre-scaled
    float* __restrict__ SC)
{
    __shared__ float Wsm[64 * 68];

    const int bidx = blockIdx.x;
    const int x = bidx & 7, j = bidx >> 3;
    const int g1 = x + 1, g2 = 32 - x, g3 = x + 9;   // group sizes
    int ts, tt;
    if (j < g1)                { ts = x;      tt = j; }
    else if (j < g1 + g2)      { ts = 31 - x; tt = j - g1; }
    else if (j < g1 + g2 + g3) { ts = x + 8;  tt = j - g1 - g2; }
    else                       { ts = 23 - x; tt = j - g1 - g2 - g3; }
    const int s0 = ts * 64, t0 = tt * 64;

    const int tid = threadIdx.x;
    const int lane = tid & 63;
    const int m = lane & 15;
    const int q = lane >> 4;
    const int strip = (tid >> 6) * 16;

    {
        const float4* gw = (const float4*)(Wf + (size_t)s0 * H_NUM);
#pragma unroll
        for (int u = 0; u < 4; u++) {
            int ch = tid + u * 256;
            float4 v = gw[ch];
            *(float4*)&Wsm[(ch >> 4) * 68 + (ch & 15) * 4] = v;
        }
    }

    short8 bf[4][4];   // [t-tile][k-step]
#pragma unroll
    for (int tile = 0; tile < 4; tile++)
#pragma unroll
        for (int ks = 0; ks < 4; ks++)
            bf[tile][ks] = *(const short8*)
                &Kb[(size_t)(t0 + tile * 16 + m) * HD_DIM + ks * 32 + q * 8];

    __syncthreads();   // Wsm ready (only barrier)

    float acc[4][4];
#pragma unroll
    for (int tile = 0; tile < 4; tile++)
#pragma unroll
        for (int r = 0; r < 4; r++) acc[tile][r] = 0.f;

    const ushort* qbase = Qb + (size_t)(s0 + strip + m) * HD_DIM + q * 8;
    const size_t hstride = (size_t)S_LEN * HD_DIM;
    const float* wrow = &Wsm[(strip + q * 4) * 68];

    auto loadQ = [&](short8* dst, int h) {
        const ushort* p = qbase + (size_t)h * hstride;
#pragma unroll
        for (int ks = 0; ks < 4; ks++) dst[ks] = *(const short8*)&p[ks * 32];
    };
    auto computeH = [&](const short8* af, int h) {
        float wv[4];
#pragma unroll
        for (int r = 0; r < 4; r++) wv[r] = wrow[r * 68 + h];
#pragma unroll
        for (int tile = 0; tile < 4; tile++) {
            floatx4 p = {0.f, 0.f, 0.f, 0.f};
#pragma unroll
            for (int ks = 0; ks < 4; ks++)
                p = __builtin_amdgcn_mfma_f32_16x16x32_bf16(af[ks], bf[tile][ks], p, 0, 0, 0);
#pragma unroll
            for (int r = 0; r < 4; r++)
                acc[tile][r] += fmaxf(p[r], 0.f) * wv[r];
        }
    };

    short8 af0[4], af1[4], af2[4], af3[4];
    loadQ(af0, 0); loadQ(af1, 1); loadQ(af2, 2);

    for (int hb = 0; hb < H_NUM; hb += 4) {
        loadQ(af3, hb + 3);
        computeH(af0, hb + 0);
        if (hb + 4 < H_NUM) loadQ(af0, hb + 4);
        computeH(af1, hb + 1);
        if (hb + 5 < H_NUM) loadQ(af1, hb + 5);
        computeH(af2, hb + 2);
        if (hb + 6 < H_NUM) loadQ(af2, hb + 6);
        computeH(af3, hb + 3);
    }

#pragma unroll
    for (int tile = 0; tile < 4; tile++)
#pragma unroll
        for (int r = 0; r < 4; r++)
            SC[(size_t)(s0 + strip + q * 4 + r) * S_LEN + t0 + tile * 16 + m] =
                acc[tile][r];
}

// ---------------------------------------------------------------------------
// Kernel 5: per-row top-512 via bitonic sort of 2048 packed u64 keys.
// ---------------------------------------------------------------------------
__device__ __forceinline__ unsigned int fkey(float f) {
    unsigned int u = __float_as_uint(f);
    return (u & 0x80000000u) ? ~u : (u | 0x80000000u);
}
__device__ __forceinline__ float fdec(unsigned int k) {
    unsigned int u = (k & 0x80000000u) ? (k & 0x7FFFFFFFu) : ~k;
    return __uint_as_float(u);
}

__global__ __launch_bounds__(256) void topk_kernel(
    const float* __restrict__ SC, float* __restrict__ outv, float* __restrict__ outi)
{
    __shared__ unsigned long long key[S_LEN];
    const int s = blockIdx.x, tid = threadIdx.x;
    for (int t = tid; t < S_LEN; t += 256) {
        float v = (t <= s) ? SC[(size_t)s * S_LEN + t] : NEG_INF_F;
        key[t] = ((unsigned long long)fkey(v) << 32) |
                 (unsigned long long)(unsigned int)(S_LEN - 1 - t);
    }
    __syncthreads();
    for (int k2 = 2; k2 <= S_LEN; k2 <<= 1) {
        for (int j = k2 >> 1; j > 0; j >>= 1) {
            for (int p = tid; p < S_LEN / 2; p += 256) {
                int i = 2 * p - (p & (j - 1));
                int ix = i + j;
                unsigned long long a = key[i], b = key[ix];
                bool up = ((i & k2) == 0);
                bool sw = up ? (a < b) : (a > b);
                if (sw) { key[i] = b; key[ix] = a; }
            }
            __syncthreads();
        }
    }
    for (int i2 = tid; i2 < TOPK_N; i2 += 256) {
        unsigned long long kv = key[i2];
        outv[(size_t)s * TOPK_N + i2] = fdec((unsigned int)(kv >> 32));
        outi[(size_t)s * TOPK_N + i2] =
            (float)(S_LEN - 1 - (int)(kv & 0xFFFFFFFFu));
    }
}

// ---------------------------------------------------------------------------
extern "C" void kernel_launch(void* const* d_in, const int* in_sizes, int n_in,
                              void* d_out, int out_size, void* d_ws, size_t ws_size,
                              hipStream_t stream)
{
    (void)in_sizes; (void)n_in; (void)out_size; (void)ws_size;
    const float* x      = (const float*)d_in[0];
    const float* q_lora = (const float*)d_in[1];
    const float* wq_b   = (const float*)d_in[2];
    const float* wk     = (const float*)d_in[3];
    const float* wproj  = (const float*)d_in[4];
    const float* knw    = (const float*)d_in[5];
    const float* knb    = (const float*)d_in[6];
    const float* cosp   = (const float*)d_in[7];
    const float* sinp   = (const float*)d_in[8];

    float* ws = (float*)d_ws;
    ushort* Qbf  = (ushort*)(ws + QBF_OFF);
    ushort* Albf = (ushort*)(ws + ALORA_OFF);
    ushort* WTbf = (ushort*)(ws + WT_OFF);
    ushort* Xbf  = (ushort*)(ws + XBF_OFF);
    ushort* WT2  = (ushort*)(ws + WT2_OFF);
    float*  Kf   = ws + KF_OFF;
    ushort* Kbf  = (ushort*)(ws + KBF_OFF);
    float*  Wf   = ws + WF_OFF;
    float*  SCb  = ws + SC_OFF;
    float*  partial = ws + SC_OFF;   // alias: consumed before SC is written

    float* outv = (float*)d_out;
    float* outi = outv + (size_t)S_LEN * TOPK_N;

    cast_bf16_kernel<<<(S_LEN * QLR_DIM) / (256 * 8), 256, 0, stream>>>(q_lora, Albf);
    cast_bf16_kernel<<<(S_LEN * D_DIM) / (256 * 8), 256, 0, stream>>>(x, Xbf);
    transpose_wqb_kernel<<<dim3(NQ_DIM / 64, QLR_DIM / 64), 256, 0, stream>>>(wq_b, WTbf);
    transpose_wkp_kernel<<<dim3(3, D_DIM / 64), 256, 0, stream>>>(wk, wproj, WT2);
    kw_mfma_kernel<<<dim3(S_LEN / 128, 3, KCHUNKS), 256, 0, stream>>>(Xbf, WT2, partial);
    kw_reduce_kernel<<<(S_LEN * 192) / 256, 256, 0, stream>>>(partial, Kf, Wf);
    knorm_rope_kernel<<<S_LEN, 128, 0, stream>>>(Kf, knw, knb, cosp, sinp, Kbf);
    qgemm_mfma_kernel<<<dim3(NQ_DIM / 128, S_LEN / 128), 256, 0, stream>>>(
        Albf, WTbf, cosp, sinp, Qbf);
    attn_mfma_kernel<<<528, 256, 0, stream>>>(Qbf, Kbf, Wf, SCb);
    topk_kernel<<<S_LEN, 256, 0, stream>>>(SCb, outv, outi);
}

// Round 7
// 401.754 us; speedup vs baseline: 1.1237x; 1.1237x over previous
//
#include <hip/hip_runtime.h>
#include <stdint.h>

#define S_LEN 2048
#define D_DIM 7168
#define H_NUM 64
#define HD_DIM 128
#define QLR_DIM 1536
#define NQ_DIM 8192      // H*HD
#define ROPE_DIM 64
#define HALF_DIM 32
#define TOPK_N 512
#define NEG_INF_F (-1e30f)
#define LN_EPS 1e-6f
#define W_SCALE 0.011048543456039806f   // 1/sqrt(64*128)

#define KCHUNKS 7
#define KCHUNK_SZ 1024

// Q fragment layout: Qfrag[h][sgrp][ks][lane] of short8 (16B chunks).
// element (s,d) at h: sgrp=s>>4, ks=d>>5, lane=(s&15)+(((d>>3)&3)<<4), j=d&7.
#define QF_HSTRIDE (128 * 4 * 64 * 8)   // elements per head = 262144

// workspace layout (float offsets)
#define QBF_OFF 0                                    // S*NQ bf16 = 8388608 floats
#define ALORA_OFF (QBF_OFF + S_LEN * NQ_DIM / 2)     // q_lora bf16
#define WT_OFF   (ALORA_OFF + S_LEN * QLR_DIM / 2)   // wq_b^T bf16
#define XBF_OFF  (WT_OFF + NQ_DIM * QLR_DIM / 2)     // x bf16: S*D/2 floats
#define WT2_OFF  (XBF_OFF + S_LEN * D_DIM / 2)       // [wk|wproj]^T bf16: 192*D/2
#define KF_OFF   (WT2_OFF + 192 * D_DIM / 2)
#define KBF_OFF  (KF_OFF + S_LEN * HD_DIM)
#define WF_OFF   (KBF_OFF + S_LEN * HD_DIM / 2)
#define SC_OFF   (WF_OFF + S_LEN * H_NUM)            // scores S*S fp32
// split-K partials (7*S*192 = 2.75M floats) alias the score region (4.19M)

typedef __attribute__((ext_vector_type(8))) short short8;
typedef __attribute__((ext_vector_type(4))) float floatx4;

__device__ __forceinline__ ushort f2bf(float f) {
    unsigned int u = __float_as_uint(f);
    u += 0x7FFFu + ((u >> 16) & 1u);   // round-to-nearest-even
    return (ushort)(u >> 16);
}
__device__ __forceinline__ unsigned int pack2bf(float lo, float hi) {
    return (unsigned int)f2bf(lo) | ((unsigned int)f2bf(hi) << 16);
}

__device__ __forceinline__ void gld_lds16(const ushort* g, ushort* l) {
    __builtin_amdgcn_global_load_lds(
        (const __attribute__((address_space(1))) unsigned int*)g,
        (__attribute__((address_space(3))) unsigned int*)l, 16, 0, 0);
}

// ---------------------------------------------------------------------------
// Kernel 0a: generic fp32 -> bf16 cast (8 elems/thread)
// ---------------------------------------------------------------------------
__global__ __launch_bounds__(256) void cast_bf16_kernel(
    const float* __restrict__ in, ushort* __restrict__ out)
{
    int g = (blockIdx.x * 256 + threadIdx.x) * 8;
    float4 a = *(const float4*)&in[g];
    float4 b = *(const float4*)&in[g + 4];
    uint4 v;
    v.x = pack2bf(a.x, a.y); v.y = pack2bf(a.z, a.w);
    v.z = pack2bf(b.x, b.y); v.w = pack2bf(b.z, b.w);
    *(uint4*)&out[g] = v;
}

// ---------------------------------------------------------------------------
// Kernel 0b: transpose+cast wq_b fp32 [QLR][NQ] -> bf16 WT [NQ][QLR].
// ---------------------------------------------------------------------------
__global__ __launch_bounds__(256) void transpose_wqb_kernel(
    const float* __restrict__ W, ushort* __restrict__ WT)
{
    __shared__ ushort tl[64][72];
    const int n0 = blockIdx.x * 64, k0 = blockIdx.y * 64;
    const int t = threadIdx.x;
    const int r = t >> 4, c4 = (t & 15) * 4;
#pragma unroll
    for (int u = 0; u < 4; u++) {
        int kk = r + u * 16;
        float4 v = *(const float4*)&W[(size_t)(k0 + kk) * NQ_DIM + n0 + c4];
        tl[c4 + 0][kk] = f2bf(v.x);
        tl[c4 + 1][kk] = f2bf(v.y);
        tl[c4 + 2][kk] = f2bf(v.z);
        tl[c4 + 3][kk] = f2bf(v.w);
    }
    __syncthreads();
#pragma unroll
    for (int u = 0; u < 2; u++) {
        int i = t + u * 256;             // 512 chunks of 16B
        int nr = i >> 3, c8 = (i & 7) * 8;
        uint4 v = *(const uint4*)&tl[nr][c8];
        *(uint4*)&WT[(size_t)(n0 + nr) * QLR_DIM + k0 + c8] = v;
    }
}

// ---------------------------------------------------------------------------
// Kernel 0c: transpose+cast [wk | wproj] -> bf16 WT2 [192][D].
// ---------------------------------------------------------------------------
__global__ __launch_bounds__(256) void transpose_wkp_kernel(
    const float* __restrict__ WK, const float* __restrict__ WP,
    ushort* __restrict__ WT2)
{
    __shared__ ushort tl[64][72];
    const int ntile = blockIdx.x;
    const int k0 = blockIdx.y * 64;
    const float* src; int ld, cbase;
    if (ntile < 2) { src = WK; ld = HD_DIM; cbase = ntile * 64; }
    else           { src = WP; ld = H_NUM; cbase = 0; }
    const int t = threadIdx.x;
    const int r = t >> 4, c4 = (t & 15) * 4;
#pragma unroll
    for (int u = 0; u < 4; u++) {
        int kk = r + u * 16;
        float4 v = *(const float4*)&src[(size_t)(k0 + kk) * ld + cbase + c4];
        tl[c4 + 0][kk] = f2bf(v.x);
        tl[c4 + 1][kk] = f2bf(v.y);
        tl[c4 + 2][kk] = f2bf(v.z);
        tl[c4 + 3][kk] = f2bf(v.w);
    }
    __syncthreads();
#pragma unroll
    for (int u = 0; u < 2; u++) {
        int i = t + u * 256;
        int nr = i >> 3, c8 = (i & 7) * 8;
        uint4 v = *(const uint4*)&tl[nr][c8];
        *(uint4*)&WT2[(size_t)(ntile * 64 + nr) * D_DIM + k0 + c8] = v;
    }
}

// ---------------------------------------------------------------------------
// Kernel 1: Q = q_lora @ wq_b via bf16 MFMA (m97 structure). Fused RoPE
// epilogue; LDS bounce then store directly in MFMA A-FRAGMENT layout
// Qfrag[h][sgrp][ks][lane] so attn's per-head loads are fully coalesced.
// ---------------------------------------------------------------------------
__global__ __launch_bounds__(256) void qgemm_mfma_kernel(
    const ushort* __restrict__ Abf,   // bf16 [S][QLR]
    const ushort* __restrict__ WT,    // bf16 [NQ][QLR]
    const float* __restrict__ cosp, const float* __restrict__ sinp,
    ushort* __restrict__ Qo)          // bf16 frag layout
{
    __shared__ ushort lds[128 * 136];          // staging aliases front
    ushort* As = lds;                          // 128 rows x 32 bf16
    ushort* Bs = lds + 4096;

    const int tid = threadIdx.x;
    const int lane = tid & 63;
    const int wave = tid >> 6;
    const int m = lane & 15;
    const int q = lane >> 4;
    const int wm = wave & 1, wn = wave >> 1;
    const int m0 = blockIdx.y * 128;
    const int n0 = blockIdx.x * 128;
    const int h = blockIdx.x;

    floatx4 acc[4][4];
#pragma unroll
    for (int i = 0; i < 4; i++)
#pragma unroll
        for (int j = 0; j < 4; j++) acc[i][j] = (floatx4){0.f, 0.f, 0.f, 0.f};

    const ushort* agp[2];
    const ushort* bgp[2];
    unsigned int sbase[2];
#pragma unroll
    for (int u = 0; u < 2; u++) {
        int s = (u * 4 + wave) * 64 + lane;
        agp[u] = Abf + (size_t)(m0 + (s >> 2)) * QLR_DIM + (s & 3) * 8;
        bgp[u] = WT + (size_t)(n0 + (s >> 2)) * QLR_DIM + (s & 3) * 8;
        sbase[u] = (unsigned int)((u * 4 + wave) * 64 * 8);
    }

    for (int kt = 0; kt < QLR_DIM; kt += 32) {
        __syncthreads();
#pragma unroll
        for (int u = 0; u < 2; u++) gld_lds16(agp[u] + kt, &As[sbase[u]]);
#pragma unroll
        for (int u = 0; u < 2; u++) gld_lds16(bgp[u] + kt, &Bs[sbase[u]]);
        __syncthreads();

        short8 af[4], bf[4];
#pragma unroll
        for (int mt = 0; mt < 4; mt++)
            af[mt] = *(const short8*)&As[(wm * 64 + mt * 16 + m) * 32 + q * 8];
#pragma unroll
        for (int nt = 0; nt < 4; nt++)
            bf[nt] = *(const short8*)&Bs[(wn * 64 + nt * 16 + m) * 32 + q * 8];
#pragma unroll
        for (int mt = 0; mt < 4; mt++)
#pragma unroll
            for (int nt = 0; nt < 4; nt++)
                acc[mt][nt] = __builtin_amdgcn_mfma_f32_16x16x32_bf16(
                    af[mt], bf[nt], acc[mt][nt], 0, 0, 0);
    }

    __syncthreads();
    ushort* ep = lds;  // 128 x (pitch 136) bf16

#pragma unroll
    for (int mt = 0; mt < 4; mt++) {
        const int srow_base = m0 + wm * 64 + mt * 16 + q * 4;
#pragma unroll
        for (int nt = 0; nt < 4; nt++) {
            const int d = wn * 64 + nt * 16 + m;
            float o[4];
            if (wn == 0) {          // d < 64 -> rope
                const int jj = d >> 1;
#pragma unroll
                for (int r = 0; r < 4; r++) {
                    float x = acc[mt][nt][r];
                    float p = __shfl_xor(x, 1, 64);
                    float c = cosp[(srow_base + r) * HALF_DIM + jj];
                    float sn = sinp[(srow_base + r) * HALF_DIM + jj];
                    o[r] = (d & 1) ? (p * sn + x * c) : (x * c - p * sn);
                }
            } else {
#pragma unroll
                for (int r = 0; r < 4; r++) o[r] = acc[mt][nt][r];
            }
#pragma unroll
            for (int r = 0; r < 4; r++)
                ep[(wm * 64 + mt * 16 + q * 4 + r) * 136 + d] = f2bf(o[r]);
        }
    }
    __syncthreads();

    // store in frag layout: chunk c within sgrp block: ks=c>>6, lane=c&63;
    // srow_local = sgl*16 + (lane&15); d0 = (ks<<5) + ((lane>>4)<<3).
    const int sgrp0 = m0 >> 4;
#pragma unroll
    for (int u = 0; u < 8; u++) {
        int i = u * 256 + tid;           // 2048 chunks of 16B
        int sgl = i >> 8, c = i & 255;
        int ks = c >> 6, ln = c & 63;
        int srow = sgl * 16 + (ln & 15);
        int d0 = (ks << 5) + ((ln >> 4) << 3);
        uint4 v = *(const uint4*)&ep[srow * 136 + d0];
        size_t dst = (size_t)h * QF_HSTRIDE +
                     ((((size_t)(sgrp0 + sgl) * 4 + ks) * 64 + ln) * 8);
        *(uint4*)&Qo[dst] = v;
    }
}

// ---------------------------------------------------------------------------
// Kernel 2: [ktmp|w] = x @ [wk|wproj] via bf16 MFMA, split-K. grid (16,3,7).
// ---------------------------------------------------------------------------
__global__ __launch_bounds__(256) void kw_mfma_kernel(
    const ushort* __restrict__ Xbf,   // bf16 [S][D]
    const ushort* __restrict__ WT2,   // bf16 [192][D]
    float* __restrict__ partial)      // [kc][S][192]
{
    __shared__ ushort As[128 * 64];   // 16 KB
    __shared__ ushort Bs[64 * 64];    //  8 KB

    const int tid = threadIdx.x;
    const int lane = tid & 63;
    const int wave = tid >> 6;
    const int m = lane & 15;
    const int q = lane >> 4;
    const int wm = wave & 1, wn = wave >> 1;
    const int m0 = blockIdx.x * 128;
    const int n0 = blockIdx.y * 64;
    const int kc = blockIdx.z;
    const size_t kbase = (size_t)kc * KCHUNK_SZ;

    const ushort* agp[4];
    unsigned int abase[4];
#pragma unroll
    for (int u = 0; u < 4; u++) {
        int s = (u * 4 + wave) * 64 + lane;
        int row = s >> 3, c = s & 7;
        int kg = c ^ (row & 7);
        agp[u] = Xbf + (size_t)(m0 + row) * D_DIM + kbase + kg * 8;
        abase[u] = (unsigned int)((u * 4 + wave) * 64 * 8);
    }
    const ushort* bgp[2];
    unsigned int bbase[2];
#pragma unroll
    for (int u = 0; u < 2; u++) {
        int s = (u * 4 + wave) * 64 + lane;
        int row = s >> 3, c = s & 7;
        int kg = c ^ (row & 7);
        bgp[u] = WT2 + (size_t)(n0 + row) * D_DIM + kbase + kg * 8;
        bbase[u] = (unsigned int)((u * 4 + wave) * 64 * 8);
    }

    floatx4 acc[4][2];
#pragma unroll
    for (int i = 0; i < 4; i++)
#pragma unroll
        for (int j = 0; j < 2; j++) acc[i][j] = (floatx4){0.f, 0.f, 0.f, 0.f};

    for (int kt = 0; kt < KCHUNK_SZ; kt += 64) {
        __syncthreads();
#pragma unroll
        for (int u = 0; u < 4; u++) gld_lds16(agp[u] + kt, &As[abase[u]]);
#pragma unroll
        for (int u = 0; u < 2; u++) gld_lds16(bgp[u] + kt, &Bs[bbase[u]]);
        __syncthreads();

        short8 af[4][2], bfr[2][2];
#pragma unroll
        for (int mt = 0; mt < 4; mt++) {
            int row = wm * 64 + mt * 16 + m;
#pragma unroll
            for (int ks = 0; ks < 2; ks++)
                af[mt][ks] = *(const short8*)
                    &As[row * 64 + ((((ks << 2) + q) ^ (m & 7)) * 8)];
        }
#pragma unroll
        for (int nt = 0; nt < 2; nt++) {
            int row = wn * 32 + nt * 16 + m;
#pragma unroll
            for (int ks = 0; ks < 2; ks++)
                bfr[nt][ks] = *(const short8*)
                    &Bs[row * 64 + ((((ks << 2) + q) ^ (m & 7)) * 8)];
        }
#pragma unroll
        for (int mt = 0; mt < 4; mt++)
#pragma unroll
            for (int nt = 0; nt < 2; nt++)
#pragma unroll
                for (int ks = 0; ks < 2; ks++)
                    acc[mt][nt] = __builtin_amdgcn_mfma_f32_16x16x32_bf16(
                        af[mt][ks], bfr[nt][ks], acc[mt][nt], 0, 0, 0);
    }

#pragma unroll
    for (int mt = 0; mt < 4; mt++) {
        int grow = m0 + wm * 64 + mt * 16 + q * 4;
#pragma unroll
        for (int nt = 0; nt < 2; nt++) {
            int gn = n0 + wn * 32 + nt * 16 + m;
#pragma unroll
            for (int r = 0; r < 4; r++)
                partial[((size_t)kc * S_LEN + grow + r) * 192 + gn] = acc[mt][nt][r];
        }
    }
}

__global__ __launch_bounds__(256) void kw_reduce_kernel(
    const float* __restrict__ partial, float* __restrict__ Ko, float* __restrict__ Wo)
{
    int g = blockIdx.x * 256 + threadIdx.x;   // < S*192
    int m = g / 192, n = g % 192;
    float s = 0.f;
#pragma unroll
    for (int c = 0; c < KCHUNKS; c++)
        s += partial[((size_t)c * S_LEN + m) * 192 + n];
    if (n < HD_DIM) Ko[(size_t)m * HD_DIM + n] = s;
    else            Wo[(size_t)m * H_NUM + (n - HD_DIM)] = s * W_SCALE;
}

// ---------------------------------------------------------------------------
// Kernel 3: per-row layernorm + interleaved RoPE on k; emits bf16 K.
// ---------------------------------------------------------------------------
__global__ __launch_bounds__(128) void knorm_rope_kernel(
    const float* __restrict__ Kf, const float* __restrict__ gw, const float* __restrict__ gb,
    const float* __restrict__ cosp, const float* __restrict__ sinp,
    ushort* __restrict__ Kbf)
{
    __shared__ float red[128];
    __shared__ float sh[128];
    const int m = blockIdx.x, t = threadIdx.x;
    float v = Kf[(size_t)m * HD_DIM + t];
    red[t] = v; __syncthreads();
    for (int off = 64; off > 0; off >>= 1) {
        if (t < off) red[t] += red[t + off];
        __syncthreads();
    }
    float mu = red[0] * (1.f / HD_DIM);
    __syncthreads();
    float dv = v - mu;
    red[t] = dv * dv; __syncthreads();
    for (int off = 64; off > 0; off >>= 1) {
        if (t < off) red[t] += red[t + off];
        __syncthreads();
    }
    float var = red[0] * (1.f / HD_DIM);
    float rs = rsqrtf(var + LN_EPS);
    float kn = dv * rs * gw[t] + gb[t];
    sh[t] = kn; __syncthreads();
    float out;
    if (t < ROPE_DIM) {
        int jj = t >> 1;
        float c = cosp[m * HALF_DIM + jj], sn = sinp[m * HALF_DIM + jj];
        out = ((t & 1) == 0) ? (sh[t] * c - sh[t + 1] * sn)
                             : (sh[t - 1] * sn + sh[t] * c);
    } else {
        out = kn;
    }
    Kbf[(size_t)m * HD_DIM + t] = f2bf(out);
}

// ---------------------------------------------------------------------------
// Kernel 4: index_score via bf16 MFMA, barrier-free head loop.
// Q read from frag layout -> per-head loads are 4 fully-coalesced 1-KB wave
// loads. K frags in registers (launch_bounds(256,2) grants the VGPR budget).
// XCD-aware tile map keeps each ts-group's Q slice L2-resident.
// ---------------------------------------------------------------------------
__global__ __launch_bounds__(256, 2) void attn_mfma_kernel(
    const ushort* __restrict__ Qb,  // bf16 frag layout [h][sgrp][ks][lane]x8
    const ushort* __restrict__ Kb,  // bf16 [S][HD]
    const float* __restrict__ Wf,   // fp32 [S][H], pre-scaled
    float* __restrict__ SC)
{
    __shared__ float Wsm[64 * 68];

    const int bidx = blockIdx.x;
    const int x = bidx & 7, j = bidx >> 3;
    const int g1 = x + 1, g2 = 32 - x, g3 = x + 9;   // group sizes (g4=24-x)
    int ts, tt;
    if (j < g1)                { ts = x;      tt = j; }
    else if (j < g1 + g2)      { ts = 31 - x; tt = j - g1; }
    else if (j < g1 + g2 + g3) { ts = x + 8;  tt = j - g1 - g2; }
    else                       { ts = 23 - x; tt = j - g1 - g2 - g3; }
    const int s0 = ts * 64, t0 = tt * 64;

    const int tid = threadIdx.x;
    const int lane = tid & 63;
    const int m = lane & 15;
    const int q = lane >> 4;
    const int strip = (tid >> 6) * 16;

    {
        const float4* gw = (const float4*)(Wf + (size_t)s0 * H_NUM);
#pragma unroll
        for (int u = 0; u < 4; u++) {
            int ch = tid + u * 256;
            float4 v = gw[ch];
            *(float4*)&Wsm[(ch >> 4) * 68 + (ch & 15) * 4] = v;
        }
    }

    short8 bf[4][4];   // [t-tile][k-step] — resident all block
#pragma unroll
    for (int tile = 0; tile < 4; tile++)
#pragma unroll
        for (int ks = 0; ks < 4; ks++)
            bf[tile][ks] = *(const short8*)
                &Kb[(size_t)(t0 + tile * 16 + m) * HD_DIM + ks * 32 + q * 8];

    __syncthreads();   // Wsm ready (only barrier)

    float acc[4][4];
#pragma unroll
    for (int tile = 0; tile < 4; tile++)
#pragma unroll
        for (int r = 0; r < 4; r++) acc[tile][r] = 0.f;

    // frag base for this wave: sgrp = ts*4 + strip/16
    const int sgrp = ts * 4 + (strip >> 4);
    const ushort* qfb = Qb + ((size_t)sgrp * 4 * 64 + lane) * 8;
    const float* wrow = &Wsm[(strip + q * 4) * 68];

    auto loadQ = [&](short8* dst, int h) {
        const ushort* p = qfb + (size_t)h * QF_HSTRIDE;
#pragma unroll
        for (int ks = 0; ks < 4; ks++) dst[ks] = *(const short8*)&p[ks * 512];
    };
    auto computeH = [&](const short8* af, int h) {
        float wv[4];
#pragma unroll
        for (int r = 0; r < 4; r++) wv[r] = wrow[r * 68 + h];
#pragma unroll
        for (int tile = 0; tile < 4; tile++) {
            floatx4 p = {0.f, 0.f, 0.f, 0.f};
#pragma unroll
            for (int ks = 0; ks < 4; ks++)
                p = __builtin_amdgcn_mfma_f32_16x16x32_bf16(af[ks], bf[tile][ks], p, 0, 0, 0);
#pragma unroll
            for (int r = 0; r < 4; r++)
                acc[tile][r] += fmaxf(p[r], 0.f) * wv[r];
        }
    };

    short8 afA[4], afB[4];
    loadQ(afA, 0);
    for (int h = 0; h < H_NUM; h += 2) {
        loadQ(afB, h + 1);
        computeH(afA, h);
        if (h + 2 < H_NUM) loadQ(afA, h + 2);
        computeH(afB, h + 1);
    }

#pragma unroll
    for (int tile = 0; tile < 4; tile++)
#pragma unroll
        for (int r = 0; r < 4; r++)
            SC[(size_t)(s0 + strip + q * 4 + r) * S_LEN + t0 + tile * 16 + m] =
                acc[tile][r];
}

// ---------------------------------------------------------------------------
// Kernel 5: per-row top-512 via bitonic sort of 2048 packed u64 keys.
// ---------------------------------------------------------------------------
__device__ __forceinline__ unsigned int fkey(float f) {
    unsigned int u = __float_as_uint(f);
    return (u & 0x80000000u) ? ~u : (u | 0x80000000u);
}
__device__ __forceinline__ float fdec(unsigned int k) {
    unsigned int u = (k & 0x80000000u) ? (k & 0x7FFFFFFFu) : ~k;
    return __uint_as_float(u);
}

__global__ __launch_bounds__(256) void topk_kernel(
    const float* __restrict__ SC, float* __restrict__ outv, float* __restrict__ outi)
{
    __shared__ unsigned long long key[S_LEN];
    const int s = blockIdx.x, tid = threadIdx.x;
    for (int t = tid; t < S_LEN; t += 256) {
        float v = (t <= s) ? SC[(size_t)s * S_LEN + t] : NEG_INF_F;
        key[t] = ((unsigned long long)fkey(v) << 32) |
                 (unsigned long long)(unsigned int)(S_LEN - 1 - t);
    }
    __syncthreads();
    for (int k2 = 2; k2 <= S_LEN; k2 <<= 1) {
        for (int j = k2 >> 1; j > 0; j >>= 1) {
            for (int p = tid; p < S_LEN / 2; p += 256) {
                int i = 2 * p - (p & (j - 1));
                int ix = i + j;
                unsigned long long a = key[i], b = key[ix];
                bool up = ((i & k2) == 0);
                bool sw = up ? (a < b) : (a > b);
                if (sw) { key[i] = b; key[ix] = a; }
            }
            __syncthreads();
        }
    }
    for (int i2 = tid; i2 < TOPK_N; i2 += 256) {
        unsigned long long kv = key[i2];
        outv[(size_t)s * TOPK_N + i2] = fdec((unsigned int)(kv >> 32));
        outi[(size_t)s * TOPK_N + i2] =
            (float)(S_LEN - 1 - (int)(kv & 0xFFFFFFFFu));
    }
}

// ---------------------------------------------------------------------------
extern "C" void kernel_launch(void* const* d_in, const int* in_sizes, int n_in,
                              void* d_out, int out_size, void* d_ws, size_t ws_size,
                              hipStream_t stream)
{
    (void)in_sizes; (void)n_in; (void)out_size; (void)ws_size;
    const float* x      = (const float*)d_in[0];
    const float* q_lora = (const float*)d_in[1];
    const float* wq_b   = (const float*)d_in[2];
    const float* wk     = (const float*)d_in[3];
    const float* wproj  = (const float*)d_in[4];
    const float* knw    = (const float*)d_in[5];
    const float* knb    = (const float*)d_in[6];
    const float* cosp   = (const float*)d_in[7];
    const float* sinp   = (const float*)d_in[8];

    float* ws = (float*)d_ws;
    ushort* Qbf  = (ushort*)(ws + QBF_OFF);
    ushort* Albf = (ushort*)(ws + ALORA_OFF);
    ushort* WTbf = (ushort*)(ws + WT_OFF);
    ushort* Xbf  = (ushort*)(ws + XBF_OFF);
    ushort* WT2  = (ushort*)(ws + WT2_OFF);
    float*  Kf   = ws + KF_OFF;
    ushort* Kbf  = (ushort*)(ws + KBF_OFF);
    float*  Wf   = ws + WF_OFF;
    float*  SCb  = ws + SC_OFF;
    float*  partial = ws + SC_OFF;   // alias: consumed before SC is written

    float* outv = (float*)d_out;
    float* outi = outv + (size_t)S_LEN * TOPK_N;

    cast_bf16_kernel<<<(S_LEN * QLR_DIM) / (256 * 8), 256, 0, stream>>>(q_lora, Albf);
    cast_bf16_kernel<<<(S_LEN * D_DIM) / (256 * 8), 256, 0, stream>>>(x, Xbf);
    transpose_wqb_kernel<<<dim3(NQ_DIM / 64, QLR_DIM / 64), 256, 0, stream>>>(wq_b, WTbf);
    transpose_wkp_kernel<<<dim3(3, D_DIM / 64), 256, 0, stream>>>(wk, wproj, WT2);
    kw_mfma_kernel<<<dim3(S_LEN / 128, 3, KCHUNKS), 256, 0, stream>>>(Xbf, WT2, partial);
    kw_reduce_kernel<<<(S_LEN * 192) / 256, 256, 0, stream>>>(partial, Kf, Wf);
    knorm_rope_kernel<<<S_LEN, 128, 0, stream>>>(Kf, knw, knb, cosp, sinp, Kbf);
    qgemm_mfma_kernel<<<dim3(NQ_DIM / 128, S_LEN / 128), 256, 0, stream>>>(
        Albf, WTbf, cosp, sinp, Qbf);
    attn_mfma_kernel<<<528, 256, 0, stream>>>(Qbf, Kbf, Wf, SCb);
    topk_kernel<<<S_LEN, 256, 0, stream>>>(SCb, outv, outi);
}

// Round 8
// 361.126 us; speedup vs baseline: 1.2501x; 1.1125x over previous
//
#include <hip/hip_runtime.h>
#include <stdint.h>

#define S_LEN 2048
#define D_DIM 7168
#define H_NUM 64
#define HD_DIM 128
#define QLR_DIM 1536
#define NQ_DIM 8192      // H*HD
#define ROPE_DIM 64
#define HALF_DIM 32
#define TOPK_N 512
#define NEG_INF_F (-1e30f)
#define LN_EPS 1e-6f
#define W_SCALE 0.011048543456039806f   // 1/sqrt(64*128)

#define KCHUNKS 7
#define KCHUNK_SZ 1024

// Q fragment layout: Qfrag[h][sgrp][ks][lane] of short8 (16B chunks).
#define QF_HSTRIDE (128 * 4 * 64 * 8)   // elements per head = 262144

// workspace layout (float offsets)
#define QBF_OFF 0                                    // S*NQ bf16 = 8388608 floats
#define ALORA_OFF (QBF_OFF + S_LEN * NQ_DIM / 2)     // q_lora bf16
#define WT_OFF   (ALORA_OFF + S_LEN * QLR_DIM / 2)   // wq_b^T bf16
#define XBF_OFF  (WT_OFF + NQ_DIM * QLR_DIM / 2)     // x bf16: S*D/2 floats
#define WT2_OFF  (XBF_OFF + S_LEN * D_DIM / 2)       // [wk|wproj]^T bf16: 192*D/2
#define KF_OFF   (WT2_OFF + 192 * D_DIM / 2)
#define KBF_OFF  (KF_OFF + S_LEN * HD_DIM)
#define WF_OFF   (KBF_OFF + S_LEN * HD_DIM / 2)
#define SC_OFF   (WF_OFF + S_LEN * H_NUM)            // scores S*S fp32
// split-K partials (7*S*192 = 2.75M floats) alias the score region (4.19M)

typedef __attribute__((ext_vector_type(8))) short short8;
typedef __attribute__((ext_vector_type(4))) float floatx4;

__device__ __forceinline__ ushort f2bf(float f) {
    unsigned int u = __float_as_uint(f);
    u += 0x7FFFu + ((u >> 16) & 1u);   // round-to-nearest-even
    return (ushort)(u >> 16);
}
__device__ __forceinline__ unsigned int pack2bf(float lo, float hi) {
    return (unsigned int)f2bf(lo) | ((unsigned int)f2bf(hi) << 16);
}

__device__ __forceinline__ void gld_lds16(const ushort* g, ushort* l) {
    __builtin_amdgcn_global_load_lds(
        (const __attribute__((address_space(1))) unsigned int*)g,
        (__attribute__((address_space(3))) unsigned int*)l, 16, 0, 0);
}

// ---------------------------------------------------------------------------
// Kernel 0a: generic fp32 -> bf16 cast (8 elems/thread)
// ---------------------------------------------------------------------------
__global__ __launch_bounds__(256) void cast_bf16_kernel(
    const float* __restrict__ in, ushort* __restrict__ out)
{
    int g = (blockIdx.x * 256 + threadIdx.x) * 8;
    float4 a = *(const float4*)&in[g];
    float4 b = *(const float4*)&in[g + 4];
    uint4 v;
    v.x = pack2bf(a.x, a.y); v.y = pack2bf(a.z, a.w);
    v.z = pack2bf(b.x, b.y); v.w = pack2bf(b.z, b.w);
    *(uint4*)&out[g] = v;
}

// ---------------------------------------------------------------------------
// Kernel 0b: transpose+cast wq_b fp32 [QLR][NQ] -> bf16 WT [NQ][QLR].
// ---------------------------------------------------------------------------
__global__ __launch_bounds__(256) void transpose_wqb_kernel(
    const float* __restrict__ W, ushort* __restrict__ WT)
{
    __shared__ ushort tl[64][72];
    const int n0 = blockIdx.x * 64, k0 = blockIdx.y * 64;
    const int t = threadIdx.x;
    const int r = t >> 4, c4 = (t & 15) * 4;
#pragma unroll
    for (int u = 0; u < 4; u++) {
        int kk = r + u * 16;
        float4 v = *(const float4*)&W[(size_t)(k0 + kk) * NQ_DIM + n0 + c4];
        tl[c4 + 0][kk] = f2bf(v.x);
        tl[c4 + 1][kk] = f2bf(v.y);
        tl[c4 + 2][kk] = f2bf(v.z);
        tl[c4 + 3][kk] = f2bf(v.w);
    }
    __syncthreads();
#pragma unroll
    for (int u = 0; u < 2; u++) {
        int i = t + u * 256;             // 512 chunks of 16B
        int nr = i >> 3, c8 = (i & 7) * 8;
        uint4 v = *(const uint4*)&tl[nr][c8];
        *(uint4*)&WT[(size_t)(n0 + nr) * QLR_DIM + k0 + c8] = v;
    }
}

// ---------------------------------------------------------------------------
// Kernel 0c: transpose+cast [wk | wproj] -> bf16 WT2 [192][D].
// ---------------------------------------------------------------------------
__global__ __launch_bounds__(256) void transpose_wkp_kernel(
    const float* __restrict__ WK, const float* __restrict__ WP,
    ushort* __restrict__ WT2)
{
    __shared__ ushort tl[64][72];
    const int ntile = blockIdx.x;
    const int k0 = blockIdx.y * 64;
    const float* src; int ld, cbase;
    if (ntile < 2) { src = WK; ld = HD_DIM; cbase = ntile * 64; }
    else           { src = WP; ld = H_NUM; cbase = 0; }
    const int t = threadIdx.x;
    const int r = t >> 4, c4 = (t & 15) * 4;
#pragma unroll
    for (int u = 0; u < 4; u++) {
        int kk = r + u * 16;
        float4 v = *(const float4*)&src[(size_t)(k0 + kk) * ld + cbase + c4];
        tl[c4 + 0][kk] = f2bf(v.x);
        tl[c4 + 1][kk] = f2bf(v.y);
        tl[c4 + 2][kk] = f2bf(v.z);
        tl[c4 + 3][kk] = f2bf(v.w);
    }
    __syncthreads();
#pragma unroll
    for (int u = 0; u < 2; u++) {
        int i = t + u * 256;
        int nr = i >> 3, c8 = (i & 7) * 8;
        uint4 v = *(const uint4*)&tl[nr][c8];
        *(uint4*)&WT2[(size_t)(ntile * 64 + nr) * D_DIM + k0 + c8] = v;
    }
}

// ---------------------------------------------------------------------------
// Kernel 1: Q = q_lora @ wq_b via bf16 MFMA (m97 structure). Fused RoPE
// epilogue; LDS bounce then store directly in MFMA A-FRAGMENT layout.
// ---------------------------------------------------------------------------
__global__ __launch_bounds__(256) void qgemm_mfma_kernel(
    const ushort* __restrict__ Abf,   // bf16 [S][QLR]
    const ushort* __restrict__ WT,    // bf16 [NQ][QLR]
    const float* __restrict__ cosp, const float* __restrict__ sinp,
    ushort* __restrict__ Qo)          // bf16 frag layout
{
    __shared__ ushort lds[128 * 136];          // staging aliases front
    ushort* As = lds;                          // 128 rows x 32 bf16
    ushort* Bs = lds + 4096;

    const int tid = threadIdx.x;
    const int lane = tid & 63;
    const int wave = tid >> 6;
    const int m = lane & 15;
    const int q = lane >> 4;
    const int wm = wave & 1, wn = wave >> 1;
    const int m0 = blockIdx.y * 128;
    const int n0 = blockIdx.x * 128;
    const int h = blockIdx.x;

    floatx4 acc[4][4];
#pragma unroll
    for (int i = 0; i < 4; i++)
#pragma unroll
        for (int j = 0; j < 4; j++) acc[i][j] = (floatx4){0.f, 0.f, 0.f, 0.f};

    const ushort* agp[2];
    const ushort* bgp[2];
    unsigned int sbase[2];
#pragma unroll
    for (int u = 0; u < 2; u++) {
        int s = (u * 4 + wave) * 64 + lane;
        agp[u] = Abf + (size_t)(m0 + (s >> 2)) * QLR_DIM + (s & 3) * 8;
        bgp[u] = WT + (size_t)(n0 + (s >> 2)) * QLR_DIM + (s & 3) * 8;
        sbase[u] = (unsigned int)((u * 4 + wave) * 64 * 8);
    }

    for (int kt = 0; kt < QLR_DIM; kt += 32) {
        __syncthreads();
#pragma unroll
        for (int u = 0; u < 2; u++) gld_lds16(agp[u] + kt, &As[sbase[u]]);
#pragma unroll
        for (int u = 0; u < 2; u++) gld_lds16(bgp[u] + kt, &Bs[sbase[u]]);
        __syncthreads();

        short8 af[4], bf[4];
#pragma unroll
        for (int mt = 0; mt < 4; mt++)
            af[mt] = *(const short8*)&As[(wm * 64 + mt * 16 + m) * 32 + q * 8];
#pragma unroll
        for (int nt = 0; nt < 4; nt++)
            bf[nt] = *(const short8*)&Bs[(wn * 64 + nt * 16 + m) * 32 + q * 8];
#pragma unroll
        for (int mt = 0; mt < 4; mt++)
#pragma unroll
            for (int nt = 0; nt < 4; nt++)
                acc[mt][nt] = __builtin_amdgcn_mfma_f32_16x16x32_bf16(
                    af[mt], bf[nt], acc[mt][nt], 0, 0, 0);
    }

    __syncthreads();
    ushort* ep = lds;  // 128 x (pitch 136) bf16

#pragma unroll
    for (int mt = 0; mt < 4; mt++) {
        const int srow_base = m0 + wm * 64 + mt * 16 + q * 4;
#pragma unroll
        for (int nt = 0; nt < 4; nt++) {
            const int d = wn * 64 + nt * 16 + m;
            float o[4];
            if (wn == 0) {          // d < 64 -> rope
                const int jj = d >> 1;
#pragma unroll
                for (int r = 0; r < 4; r++) {
                    float x = acc[mt][nt][r];
                    float p = __shfl_xor(x, 1, 64);
                    float c = cosp[(srow_base + r) * HALF_DIM + jj];
                    float sn = sinp[(srow_base + r) * HALF_DIM + jj];
                    o[r] = (d & 1) ? (p * sn + x * c) : (x * c - p * sn);
                }
            } else {
#pragma unroll
                for (int r = 0; r < 4; r++) o[r] = acc[mt][nt][r];
            }
#pragma unroll
            for (int r = 0; r < 4; r++)
                ep[(wm * 64 + mt * 16 + q * 4 + r) * 136 + d] = f2bf(o[r]);
        }
    }
    __syncthreads();

    const int sgrp0 = m0 >> 4;
#pragma unroll
    for (int u = 0; u < 8; u++) {
        int i = u * 256 + tid;           // 2048 chunks of 16B
        int sgl = i >> 8, c = i & 255;
        int ks = c >> 6, ln = c & 63;
        int srow = sgl * 16 + (ln & 15);
        int d0 = (ks << 5) + ((ln >> 4) << 3);
        uint4 v = *(const uint4*)&ep[srow * 136 + d0];
        size_t dst = (size_t)h * QF_HSTRIDE +
                     ((((size_t)(sgrp0 + sgl) * 4 + ks) * 64 + ln) * 8);
        *(uint4*)&Qo[dst] = v;
    }
}

// ---------------------------------------------------------------------------
// Kernel 2: [ktmp|w] = x @ [wk|wproj] via bf16 MFMA, split-K. grid (16,3,7).
// ---------------------------------------------------------------------------
__global__ __launch_bounds__(256) void kw_mfma_kernel(
    const ushort* __restrict__ Xbf,   // bf16 [S][D]
    const ushort* __restrict__ WT2,   // bf16 [192][D]
    float* __restrict__ partial)      // [kc][S][192]
{
    __shared__ ushort As[128 * 64];   // 16 KB
    __shared__ ushort Bs[64 * 64];    //  8 KB

    const int tid = threadIdx.x;
    const int lane = tid & 63;
    const int wave = tid >> 6;
    const int m = lane & 15;
    const int q = lane >> 4;
    const int wm = wave & 1, wn = wave >> 1;
    const int m0 = blockIdx.x * 128;
    const int n0 = blockIdx.y * 64;
    const int kc = blockIdx.z;
    const size_t kbase = (size_t)kc * KCHUNK_SZ;

    const ushort* agp[4];
    unsigned int abase[4];
#pragma unroll
    for (int u = 0; u < 4; u++) {
        int s = (u * 4 + wave) * 64 + lane;
        int row = s >> 3, c = s & 7;
        int kg = c ^ (row & 7);
        agp[u] = Xbf + (size_t)(m0 + row) * D_DIM + kbase + kg * 8;
        abase[u] = (unsigned int)((u * 4 + wave) * 64 * 8);
    }
    const ushort* bgp[2];
    unsigned int bbase[2];
#pragma unroll
    for (int u = 0; u < 2; u++) {
        int s = (u * 4 + wave) * 64 + lane;
        int row = s >> 3, c = s & 7;
        int kg = c ^ (row & 7);
        bgp[u] = WT2 + (size_t)(n0 + row) * D_DIM + kbase + kg * 8;
        bbase[u] = (unsigned int)((u * 4 + wave) * 64 * 8);
    }

    floatx4 acc[4][2];
#pragma unroll
    for (int i = 0; i < 4; i++)
#pragma unroll
        for (int j = 0; j < 2; j++) acc[i][j] = (floatx4){0.f, 0.f, 0.f, 0.f};

    for (int kt = 0; kt < KCHUNK_SZ; kt += 64) {
        __syncthreads();
#pragma unroll
        for (int u = 0; u < 4; u++) gld_lds16(agp[u] + kt, &As[abase[u]]);
#pragma unroll
        for (int u = 0; u < 2; u++) gld_lds16(bgp[u] + kt, &Bs[bbase[u]]);
        __syncthreads();

        short8 af[4][2], bfr[2][2];
#pragma unroll
        for (int mt = 0; mt < 4; mt++) {
            int row = wm * 64 + mt * 16 + m;
#pragma unroll
            for (int ks = 0; ks < 2; ks++)
                af[mt][ks] = *(const short8*)
                    &As[row * 64 + ((((ks << 2) + q) ^ (m & 7)) * 8)];
        }
#pragma unroll
        for (int nt = 0; nt < 2; nt++) {
            int row = wn * 32 + nt * 16 + m;
#pragma unroll
            for (int ks = 0; ks < 2; ks++)
                bfr[nt][ks] = *(const short8*)
                    &Bs[row * 64 + ((((ks << 2) + q) ^ (m & 7)) * 8)];
        }
#pragma unroll
        for (int mt = 0; mt < 4; mt++)
#pragma unroll
            for (int nt = 0; nt < 2; nt++)
#pragma unroll
                for (int ks = 0; ks < 2; ks++)
                    acc[mt][nt] = __builtin_amdgcn_mfma_f32_16x16x32_bf16(
                        af[mt][ks], bfr[nt][ks], acc[mt][nt], 0, 0, 0);
    }

#pragma unroll
    for (int mt = 0; mt < 4; mt++) {
        int grow = m0 + wm * 64 + mt * 16 + q * 4;
#pragma unroll
        for (int nt = 0; nt < 2; nt++) {
            int gn = n0 + wn * 32 + nt * 16 + m;
#pragma unroll
            for (int r = 0; r < 4; r++)
                partial[((size_t)kc * S_LEN + grow + r) * 192 + gn] = acc[mt][nt][r];
        }
    }
}

__global__ __launch_bounds__(256) void kw_reduce_kernel(
    const float* __restrict__ partial, float* __restrict__ Ko, float* __restrict__ Wo)
{
    int g = blockIdx.x * 256 + threadIdx.x;   // < S*192
    int m = g / 192, n = g % 192;
    float s = 0.f;
#pragma unroll
    for (int c = 0; c < KCHUNKS; c++)
        s += partial[((size_t)c * S_LEN + m) * 192 + n];
    if (n < HD_DIM) Ko[(size_t)m * HD_DIM + n] = s;
    else            Wo[(size_t)m * H_NUM + (n - HD_DIM)] = s * W_SCALE;
}

// ---------------------------------------------------------------------------
// Kernel 3: per-row layernorm + interleaved RoPE on k; emits bf16 K.
// ---------------------------------------------------------------------------
__global__ __launch_bounds__(128) void knorm_rope_kernel(
    const float* __restrict__ Kf, const float* __restrict__ gw, const float* __restrict__ gb,
    const float* __restrict__ cosp, const float* __restrict__ sinp,
    ushort* __restrict__ Kbf)
{
    __shared__ float red[128];
    __shared__ float sh[128];
    const int m = blockIdx.x, t = threadIdx.x;
    float v = Kf[(size_t)m * HD_DIM + t];
    red[t] = v; __syncthreads();
    for (int off = 64; off > 0; off >>= 1) {
        if (t < off) red[t] += red[t + off];
        __syncthreads();
    }
    float mu = red[0] * (1.f / HD_DIM);
    __syncthreads();
    float dv = v - mu;
    red[t] = dv * dv; __syncthreads();
    for (int off = 64; off > 0; off >>= 1) {
        if (t < off) red[t] += red[t + off];
        __syncthreads();
    }
    float var = red[0] * (1.f / HD_DIM);
    float rs = rsqrtf(var + LN_EPS);
    float kn = dv * rs * gw[t] + gb[t];
    sh[t] = kn; __syncthreads();
    float out;
    if (t < ROPE_DIM) {
        int jj = t >> 1;
        float c = cosp[m * HALF_DIM + jj], sn = sinp[m * HALF_DIM + jj];
        out = ((t & 1) == 0) ? (sh[t] * c - sh[t + 1] * sn)
                             : (sh[t - 1] * sn + sh[t] * c);
    } else {
        out = kn;
    }
    Kbf[(size_t)m * HD_DIM + t] = f2bf(out);
}

// ---------------------------------------------------------------------------
// Kernel 4: index_score via bf16 MFMA, barrier-free head loop.
// ---------------------------------------------------------------------------
__global__ __launch_bounds__(256, 2) void attn_mfma_kernel(
    const ushort* __restrict__ Qb,  // bf16 frag layout [h][sgrp][ks][lane]x8
    const ushort* __restrict__ Kb,  // bf16 [S][HD]
    const float* __restrict__ Wf,   // fp32 [S][H], pre-scaled
    float* __restrict__ SC)
{
    __shared__ float Wsm[64 * 68];

    const int bidx = blockIdx.x;
    const int x = bidx & 7, j = bidx >> 3;
    const int g1 = x + 1, g2 = 32 - x, g3 = x + 9;   // group sizes (g4=24-x)
    int ts, tt;
    if (j < g1)                { ts = x;      tt = j; }
    else if (j < g1 + g2)      { ts = 31 - x; tt = j - g1; }
    else if (j < g1 + g2 + g3) { ts = x + 8;  tt = j - g1 - g2; }
    else                       { ts = 23 - x; tt = j - g1 - g2 - g3; }
    const int s0 = ts * 64, t0 = tt * 64;

    const int tid = threadIdx.x;
    const int lane = tid & 63;
    const int m = lane & 15;
    const int q = lane >> 4;
    const int strip = (tid >> 6) * 16;

    {
        const float4* gw = (const float4*)(Wf + (size_t)s0 * H_NUM);
#pragma unroll
        for (int u = 0; u < 4; u++) {
            int ch = tid + u * 256;
            float4 v = gw[ch];
            *(float4*)&Wsm[(ch >> 4) * 68 + (ch & 15) * 4] = v;
        }
    }

    short8 bf[4][4];   // [t-tile][k-step] — resident all block
#pragma unroll
    for (int tile = 0; tile < 4; tile++)
#pragma unroll
        for (int ks = 0; ks < 4; ks++)
            bf[tile][ks] = *(const short8*)
                &Kb[(size_t)(t0 + tile * 16 + m) * HD_DIM + ks * 32 + q * 8];

    __syncthreads();   // Wsm ready (only barrier)

    float acc[4][4];
#pragma unroll
    for (int tile = 0; tile < 4; tile++)
#pragma unroll
        for (int r = 0; r < 4; r++) acc[tile][r] = 0.f;

    const int sgrp = ts * 4 + (strip >> 4);
    const ushort* qfb = Qb + ((size_t)sgrp * 4 * 64 + lane) * 8;
    const float* wrow = &Wsm[(strip + q * 4) * 68];

    auto loadQ = [&](short8* dst, int h) {
        const ushort* p = qfb + (size_t)h * QF_HSTRIDE;
#pragma unroll
        for (int ks = 0; ks < 4; ks++) dst[ks] = *(const short8*)&p[ks * 512];
    };
    auto computeH = [&](const short8* af, int h) {
        float wv[4];
#pragma unroll
        for (int r = 0; r < 4; r++) wv[r] = wrow[r * 68 + h];
#pragma unroll
        for (int tile = 0; tile < 4; tile++) {
            floatx4 p = {0.f, 0.f, 0.f, 0.f};
#pragma unroll
            for (int ks = 0; ks < 4; ks++)
                p = __builtin_amdgcn_mfma_f32_16x16x32_bf16(af[ks], bf[tile][ks], p, 0, 0, 0);
#pragma unroll
            for (int r = 0; r < 4; r++)
                acc[tile][r] += fmaxf(p[r], 0.f) * wv[r];
        }
    };

    short8 afA[4], afB[4];
    loadQ(afA, 0);
    for (int h = 0; h < H_NUM; h += 2) {
        loadQ(afB, h + 1);
        computeH(afA, h);
        if (h + 2 < H_NUM) loadQ(afA, h + 2);
        computeH(afB, h + 1);
    }

#pragma unroll
    for (int tile = 0; tile < 4; tile++)
#pragma unroll
        for (int r = 0; r < 4; r++)
            SC[(size_t)(s0 + strip + q * 4 + r) * S_LEN + t0 + tile * 16 + m] =
                acc[tile][r];
}

// ---------------------------------------------------------------------------
// Kernel 5: per-row top-512, u32 compressed keys, causal-length-adaptive
// partial bitonic (chunk sorts + bitonic top-512 merges).
// key = (fkey(v) & 0xFFFFF800) | (2047-t): 21 value bits, 11 index bits.
// Exact fp32 vals recovered from LDS val[] by decoded index at output.
// ---------------------------------------------------------------------------
__device__ __forceinline__ unsigned int fkey(float f) {
    unsigned int u = __float_as_uint(f);
    return (u & 0x80000000u) ? ~u : (u | 0x80000000u);
}

__global__ __launch_bounds__(256) void topk_kernel(
    const float* __restrict__ SC, float* __restrict__ outv, float* __restrict__ outi)
{
    __shared__ unsigned int key[S_LEN];
    __shared__ float val[S_LEN];
    const int s = blockIdx.x, tid = threadIdx.x;
    const int nchunks = (s >> 9) + 1;          // 1..4 active 512-chunks
    const int nact = nchunks << 9;

    for (int t = tid; t < nact; t += 256) {
        float v = (t <= s) ? SC[(size_t)s * S_LEN + t] : NEG_INF_F;
        val[t] = v;
        key[t] = (fkey(v) & 0xFFFFF800u) | (unsigned int)(S_LEN - 1 - t);
    }
    __syncthreads();

    // Phase 1: sort each active 512-chunk descending (local-index network)
    for (int k2 = 2; k2 <= 512; k2 <<= 1) {
        for (int j = k2 >> 1; j > 0; j >>= 1) {
            for (int p = tid; p < (nact >> 1); p += 256) {
                int i = 2 * p - (p & (j - 1));
                int il = i & 511;
                unsigned int a = key[i], b = key[i + j];
                bool up = ((il & k2) == 0);
                bool sw = up ? (a < b) : (a > b);
                if (sw) { key[i] = b; key[i + j] = a; }
            }
            __syncthreads();
        }
    }

    // Phase 2: fold chunks c=1.. into chunk 0 (top-512 of union each time)
    for (int c = 1; c < nchunks; c++) {
        for (int p = tid; p < 512; p += 256) {
            unsigned int a = key[p], b = key[(c << 9) + 511 - p];
            key[p] = a > b ? a : b;    // bitonic, contains top-512
        }
        __syncthreads();
        for (int j = 256; j > 0; j >>= 1) {      // bitonic merge, descending
            int p = tid;                          // 256 pairs exactly
            int i = 2 * p - (p & (j - 1));
            unsigned int a = key[i], b = key[i + j];
            if (a < b) { key[i] = b; key[i + j] = a; }
            __syncthreads();
        }
    }

    for (int i2 = tid; i2 < TOPK_N; i2 += 256) {
        unsigned int kv = key[i2];
        int t = S_LEN - 1 - (int)(kv & 0x7FFu);
        outv[(size_t)s * TOPK_N + i2] = val[t];
        outi[(size_t)s * TOPK_N + i2] = (float)t;
    }
}

// ---------------------------------------------------------------------------
extern "C" void kernel_launch(void* const* d_in, const int* in_sizes, int n_in,
                              void* d_out, int out_size, void* d_ws, size_t ws_size,
                              hipStream_t stream)
{
    (void)in_sizes; (void)n_in; (void)out_size; (void)ws_size;
    const float* x      = (const float*)d_in[0];
    const float* q_lora = (const float*)d_in[1];
    const float* wq_b   = (const float*)d_in[2];
    const float* wk     = (const float*)d_in[3];
    const float* wproj  = (const float*)d_in[4];
    const float* knw    = (const float*)d_in[5];
    const float* knb    = (const float*)d_in[6];
    const float* cosp   = (const float*)d_in[7];
    const float* sinp   = (const float*)d_in[8];

    float* ws = (float*)d_ws;
    ushort* Qbf  = (ushort*)(ws + QBF_OFF);
    ushort* Albf = (ushort*)(ws + ALORA_OFF);
    ushort* WTbf = (ushort*)(ws + WT_OFF);
    ushort* Xbf  = (ushort*)(ws + XBF_OFF);
    ushort* WT2  = (ushort*)(ws + WT2_OFF);
    float*  Kf   = ws + KF_OFF;
    ushort* Kbf  = (ushort*)(ws + KBF_OFF);
    float*  Wf   = ws + WF_OFF;
    float*  SCb  = ws + SC_OFF;
    float*  partial = ws + SC_OFF;   // alias: consumed before SC is written

    float* outv = (float*)d_out;
    float* outi = outv + (size_t)S_LEN * TOPK_N;

    cast_bf16_kernel<<<(S_LEN * QLR_DIM) / (256 * 8), 256, 0, stream>>>(q_lora, Albf);
    cast_bf16_kernel<<<(S_LEN * D_DIM) / (256 * 8), 256, 0, stream>>>(x, Xbf);
    transpose_wqb_kernel<<<dim3(NQ_DIM / 64, QLR_DIM / 64), 256, 0, stream>>>(wq_b, WTbf);
    transpose_wkp_kernel<<<dim3(3, D_DIM / 64), 256, 0, stream>>>(wk, wproj, WT2);
    kw_mfma_kernel<<<dim3(S_LEN / 128, 3, KCHUNKS), 256, 0, stream>>>(Xbf, WT2, partial);
    kw_reduce_kernel<<<(S_LEN * 192) / 256, 256, 0, stream>>>(partial, Kf, Wf);
    knorm_rope_kernel<<<S_LEN, 128, 0, stream>>>(Kf, knw, knb, cosp, sinp, Kbf);
    qgemm_mfma_kernel<<<dim3(NQ_DIM / 128, S_LEN / 128), 256, 0, stream>>>(
        Albf, WTbf, cosp, sinp, Qbf);
    attn_mfma_kernel<<<528, 256, 0, stream>>>(Qbf, Kbf, Wf, SCb);
    topk_kernel<<<S_LEN, 256, 0, stream>>>(SCb, outv, outi);
}

// Round 9
// 349.190 us; speedup vs baseline: 1.2928x; 1.0342x over previous
//
#include <hip/hip_runtime.h>
#include <stdint.h>

#define S_LEN 2048
#define D_DIM 7168
#define H_NUM 64
#define HD_DIM 128
#define QLR_DIM 1536
#define NQ_DIM 8192      // H*HD
#define ROPE_DIM 64
#define HALF_DIM 32
#define TOPK_N 512
#define NEG_INF_F (-1e30f)
#define LN_EPS 1e-6f
#define W_SCALE 0.011048543456039806f   // 1/sqrt(64*128)

#define KCHUNKS 7
#define KCHUNK_SZ 1024

// Q fragment layout: Qfrag[h][sgrp][ks][lane] of short8 (16B chunks).
#define QF_HSTRIDE (128 * 4 * 64 * 8)   // elements per head = 262144

// workspace layout (float offsets)
#define QBF_OFF 0                                    // S*NQ bf16 = 8388608 floats
#define ALORA_OFF (QBF_OFF + S_LEN * NQ_DIM / 2)     // q_lora bf16
#define WT_OFF   (ALORA_OFF + S_LEN * QLR_DIM / 2)   // wq_b^T bf16
#define XBF_OFF  (WT_OFF + NQ_DIM * QLR_DIM / 2)     // x bf16: S*D/2 floats
#define WT2_OFF  (XBF_OFF + S_LEN * D_DIM / 2)       // [wk|wproj]^T bf16: 192*D/2
#define KF_OFF   (WT2_OFF + 192 * D_DIM / 2)
#define KBF_OFF  (KF_OFF + S_LEN * HD_DIM)
#define WF_OFF   (KBF_OFF + S_LEN * HD_DIM / 2)
#define SC_OFF   (WF_OFF + S_LEN * H_NUM)            // scores S*S fp32
// split-K partials (7*S*192 = 2.75M floats) alias the score region (4.19M)

typedef __attribute__((ext_vector_type(8))) short short8;
typedef __attribute__((ext_vector_type(4))) float floatx4;

__device__ __forceinline__ ushort f2bf(float f) {
    unsigned int u = __float_as_uint(f);
    u += 0x7FFFu + ((u >> 16) & 1u);   // round-to-nearest-even
    return (ushort)(u >> 16);
}
__device__ __forceinline__ unsigned int pack2bf(float lo, float hi) {
    return (unsigned int)f2bf(lo) | ((unsigned int)f2bf(hi) << 16);
}

__device__ __forceinline__ void gld_lds16(const ushort* g, ushort* l) {
    __builtin_amdgcn_global_load_lds(
        (const __attribute__((address_space(1))) unsigned int*)g,
        (__attribute__((address_space(3))) unsigned int*)l, 16, 0, 0);
}

// ---------------------------------------------------------------------------
// Kernel 0a: generic fp32 -> bf16 cast (8 elems/thread)
// ---------------------------------------------------------------------------
__global__ __launch_bounds__(256) void cast_bf16_kernel(
    const float* __restrict__ in, ushort* __restrict__ out)
{
    int g = (blockIdx.x * 256 + threadIdx.x) * 8;
    float4 a = *(const float4*)&in[g];
    float4 b = *(const float4*)&in[g + 4];
    uint4 v;
    v.x = pack2bf(a.x, a.y); v.y = pack2bf(a.z, a.w);
    v.z = pack2bf(b.x, b.y); v.w = pack2bf(b.z, b.w);
    *(uint4*)&out[g] = v;
}

// ---------------------------------------------------------------------------
// Kernel 0b: transpose+cast wq_b fp32 [QLR][NQ] -> bf16 WT [NQ][QLR].
// ---------------------------------------------------------------------------
__global__ __launch_bounds__(256) void transpose_wqb_kernel(
    const float* __restrict__ W, ushort* __restrict__ WT)
{
    __shared__ ushort tl[64][72];
    const int n0 = blockIdx.x * 64, k0 = blockIdx.y * 64;
    const int t = threadIdx.x;
    const int r = t >> 4, c4 = (t & 15) * 4;
#pragma unroll
    for (int u = 0; u < 4; u++) {
        int kk = r + u * 16;
        float4 v = *(const float4*)&W[(size_t)(k0 + kk) * NQ_DIM + n0 + c4];
        tl[c4 + 0][kk] = f2bf(v.x);
        tl[c4 + 1][kk] = f2bf(v.y);
        tl[c4 + 2][kk] = f2bf(v.z);
        tl[c4 + 3][kk] = f2bf(v.w);
    }
    __syncthreads();
#pragma unroll
    for (int u = 0; u < 2; u++) {
        int i = t + u * 256;             // 512 chunks of 16B
        int nr = i >> 3, c8 = (i & 7) * 8;
        uint4 v = *(const uint4*)&tl[nr][c8];
        *(uint4*)&WT[(size_t)(n0 + nr) * QLR_DIM + k0 + c8] = v;
    }
}

// ---------------------------------------------------------------------------
// Kernel 0c: transpose+cast [wk | wproj] -> bf16 WT2 [192][D].
// ---------------------------------------------------------------------------
__global__ __launch_bounds__(256) void transpose_wkp_kernel(
    const float* __restrict__ WK, const float* __restrict__ WP,
    ushort* __restrict__ WT2)
{
    __shared__ ushort tl[64][72];
    const int ntile = blockIdx.x;
    const int k0 = blockIdx.y * 64;
    const float* src; int ld, cbase;
    if (ntile < 2) { src = WK; ld = HD_DIM; cbase = ntile * 64; }
    else           { src = WP; ld = H_NUM; cbase = 0; }
    const int t = threadIdx.x;
    const int r = t >> 4, c4 = (t & 15) * 4;
#pragma unroll
    for (int u = 0; u < 4; u++) {
        int kk = r + u * 16;
        float4 v = *(const float4*)&src[(size_t)(k0 + kk) * ld + cbase + c4];
        tl[c4 + 0][kk] = f2bf(v.x);
        tl[c4 + 1][kk] = f2bf(v.y);
        tl[c4 + 2][kk] = f2bf(v.z);
        tl[c4 + 3][kk] = f2bf(v.w);
    }
    __syncthreads();
#pragma unroll
    for (int u = 0; u < 2; u++) {
        int i = t + u * 256;
        int nr = i >> 3, c8 = (i & 7) * 8;
        uint4 v = *(const uint4*)&tl[nr][c8];
        *(uint4*)&WT2[(size_t)(ntile * 64 + nr) * D_DIM + k0 + c8] = v;
    }
}

// ---------------------------------------------------------------------------
// Kernel 1: Q = q_lora @ wq_b via bf16 MFMA. BK=64, XOR-8 swizzled LDS
// (conflict-free ds_read_b128), 24 iterations (2x MFMA per barrier drain).
// Fused RoPE epilogue; LDS bounce; store in MFMA A-fragment layout.
// ---------------------------------------------------------------------------
__global__ __launch_bounds__(256) void qgemm_mfma_kernel(
    const ushort* __restrict__ Abf,   // bf16 [S][QLR]
    const ushort* __restrict__ WT,    // bf16 [NQ][QLR]
    const float* __restrict__ cosp, const float* __restrict__ sinp,
    ushort* __restrict__ Qo)          // bf16 frag layout
{
    __shared__ ushort lds[128 * 136];          // 34,816 B; staging aliases front
    ushort* As = lds;                          // 128 rows x 64 bf16 (128B rows)
    ushort* Bs = lds + 8192;                   // 128 rows x 64 bf16

    const int tid = threadIdx.x;
    const int lane = tid & 63;
    const int wave = tid >> 6;
    const int m = lane & 15;
    const int q = lane >> 4;
    const int wm = wave & 1, wn = wave >> 1;
    const int m0 = blockIdx.y * 128;
    const int n0 = blockIdx.x * 128;
    const int h = blockIdx.x;

    floatx4 acc[4][4];
#pragma unroll
    for (int i = 0; i < 4; i++)
#pragma unroll
        for (int j = 0; j < 4; j++) acc[i][j] = (floatx4){0.f, 0.f, 0.f, 0.f};

    // staging: 1024 slots of 16B per operand; slot s: row=s>>3, c=s&7,
    // global k-chunk kg = c ^ (row&7)  (source swizzle -> swizzled LDS).
    const ushort* agp[4];
    const ushort* bgp[4];
    unsigned int sbase[4];
#pragma unroll
    for (int u = 0; u < 4; u++) {
        int s = (u * 4 + wave) * 64 + lane;
        int row = s >> 3, c = s & 7;
        int kg = c ^ (row & 7);
        agp[u] = Abf + (size_t)(m0 + row) * QLR_DIM + kg * 8;
        bgp[u] = WT + (size_t)(n0 + row) * QLR_DIM + kg * 8;
        sbase[u] = (unsigned int)((u * 4 + wave) * 64 * 8);
    }

    for (int kt = 0; kt < QLR_DIM; kt += 64) {
        __syncthreads();
#pragma unroll
        for (int u = 0; u < 4; u++) gld_lds16(agp[u] + kt, &As[sbase[u]]);
#pragma unroll
        for (int u = 0; u < 4; u++) gld_lds16(bgp[u] + kt, &Bs[sbase[u]]);
        __syncthreads();

        short8 af[4][2], bf[4][2];
#pragma unroll
        for (int mt = 0; mt < 4; mt++) {
            int row = wm * 64 + mt * 16 + m;
#pragma unroll
            for (int ks = 0; ks < 2; ks++)
                af[mt][ks] = *(const short8*)
                    &As[row * 64 + ((((ks << 2) + q) ^ (m & 7)) * 8)];
        }
#pragma unroll
        for (int nt = 0; nt < 4; nt++) {
            int row = wn * 64 + nt * 16 + m;
#pragma unroll
            for (int ks = 0; ks < 2; ks++)
                bf[nt][ks] = *(const short8*)
                    &Bs[row * 64 + ((((ks << 2) + q) ^ (m & 7)) * 8)];
        }
#pragma unroll
        for (int mt = 0; mt < 4; mt++)
#pragma unroll
            for (int nt = 0; nt < 4; nt++)
#pragma unroll
                for (int ks = 0; ks < 2; ks++)
                    acc[mt][nt] = __builtin_amdgcn_mfma_f32_16x16x32_bf16(
                        af[mt][ks], bf[nt][ks], acc[mt][nt], 0, 0, 0);
    }

    __syncthreads();
    ushort* ep = lds;  // 128 x (pitch 136) bf16

#pragma unroll
    for (int mt = 0; mt < 4; mt++) {
        const int srow_base = m0 + wm * 64 + mt * 16 + q * 4;
#pragma unroll
        for (int nt = 0; nt < 4; nt++) {
            const int d = wn * 64 + nt * 16 + m;
            float o[4];
            if (wn == 0) {          // d < 64 -> rope
                const int jj = d >> 1;
#pragma unroll
                for (int r = 0; r < 4; r++) {
                    float x = acc[mt][nt][r];
                    float p = __shfl_xor(x, 1, 64);
                    float c = cosp[(srow_base + r) * HALF_DIM + jj];
                    float sn = sinp[(srow_base + r) * HALF_DIM + jj];
                    o[r] = (d & 1) ? (p * sn + x * c) : (x * c - p * sn);
                }
            } else {
#pragma unroll
                for (int r = 0; r < 4; r++) o[r] = acc[mt][nt][r];
            }
#pragma unroll
            for (int r = 0; r < 4; r++)
                ep[(wm * 64 + mt * 16 + q * 4 + r) * 136 + d] = f2bf(o[r]);
        }
    }
    __syncthreads();

    const int sgrp0 = m0 >> 4;
#pragma unroll
    for (int u = 0; u < 8; u++) {
        int i = u * 256 + tid;           // 2048 chunks of 16B
        int sgl = i >> 8, c = i & 255;
        int ks = c >> 6, ln = c & 63;
        int srow = sgl * 16 + (ln & 15);
        int d0 = (ks << 5) + ((ln >> 4) << 3);
        uint4 v = *(const uint4*)&ep[srow * 136 + d0];
        size_t dst = (size_t)h * QF_HSTRIDE +
                     ((((size_t)(sgrp0 + sgl) * 4 + ks) * 64 + ln) * 8);
        *(uint4*)&Qo[dst] = v;
    }
}

// ---------------------------------------------------------------------------
// Kernel 2: [ktmp|w] = x @ [wk|wproj] via bf16 MFMA, split-K. grid (16,3,7).
// ---------------------------------------------------------------------------
__global__ __launch_bounds__(256) void kw_mfma_kernel(
    const ushort* __restrict__ Xbf,   // bf16 [S][D]
    const ushort* __restrict__ WT2,   // bf16 [192][D]
    float* __restrict__ partial)      // [kc][S][192]
{
    __shared__ ushort As[128 * 64];   // 16 KB
    __shared__ ushort Bs[64 * 64];    //  8 KB

    const int tid = threadIdx.x;
    const int lane = tid & 63;
    const int wave = tid >> 6;
    const int m = lane & 15;
    const int q = lane >> 4;
    const int wm = wave & 1, wn = wave >> 1;
    const int m0 = blockIdx.x * 128;
    const int n0 = blockIdx.y * 64;
    const int kc = blockIdx.z;
    const size_t kbase = (size_t)kc * KCHUNK_SZ;

    const ushort* agp[4];
    unsigned int abase[4];
#pragma unroll
    for (int u = 0; u < 4; u++) {
        int s = (u * 4 + wave) * 64 + lane;
        int row = s >> 3, c = s & 7;
        int kg = c ^ (row & 7);
        agp[u] = Xbf + (size_t)(m0 + row) * D_DIM + kbase + kg * 8;
        abase[u] = (unsigned int)((u * 4 + wave) * 64 * 8);
    }
    const ushort* bgp[2];
    unsigned int bbase[2];
#pragma unroll
    for (int u = 0; u < 2; u++) {
        int s = (u * 4 + wave) * 64 + lane;
        int row = s >> 3, c = s & 7;
        int kg = c ^ (row & 7);
        bgp[u] = WT2 + (size_t)(n0 + row) * D_DIM + kbase + kg * 8;
        bbase[u] = (unsigned int)((u * 4 + wave) * 64 * 8);
    }

    floatx4 acc[4][2];
#pragma unroll
    for (int i = 0; i < 4; i++)
#pragma unroll
        for (int j = 0; j < 2; j++) acc[i][j] = (floatx4){0.f, 0.f, 0.f, 0.f};

    for (int kt = 0; kt < KCHUNK_SZ; kt += 64) {
        __syncthreads();
#pragma unroll
        for (int u = 0; u < 4; u++) gld_lds16(agp[u] + kt, &As[abase[u]]);
#pragma unroll
        for (int u = 0; u < 2; u++) gld_lds16(bgp[u] + kt, &Bs[bbase[u]]);
        __syncthreads();

        short8 af[4][2], bfr[2][2];
#pragma unroll
        for (int mt = 0; mt < 4; mt++) {
            int row = wm * 64 + mt * 16 + m;
#pragma unroll
            for (int ks = 0; ks < 2; ks++)
                af[mt][ks] = *(const short8*)
                    &As[row * 64 + ((((ks << 2) + q) ^ (m & 7)) * 8)];
        }
#pragma unroll
        for (int nt = 0; nt < 2; nt++) {
            int row = wn * 32 + nt * 16 + m;
#pragma unroll
            for (int ks = 0; ks < 2; ks++)
                bfr[nt][ks] = *(const short8*)
                    &Bs[row * 64 + ((((ks << 2) + q) ^ (m & 7)) * 8)];
        }
#pragma unroll
        for (int mt = 0; mt < 4; mt++)
#pragma unroll
            for (int nt = 0; nt < 2; nt++)
#pragma unroll
                for (int ks = 0; ks < 2; ks++)
                    acc[mt][nt] = __builtin_amdgcn_mfma_f32_16x16x32_bf16(
                        af[mt][ks], bfr[nt][ks], acc[mt][nt], 0, 0, 0);
    }

#pragma unroll
    for (int mt = 0; mt < 4; mt++) {
        int grow = m0 + wm * 64 + mt * 16 + q * 4;
#pragma unroll
        for (int nt = 0; nt < 2; nt++) {
            int gn = n0 + wn * 32 + nt * 16 + m;
#pragma unroll
            for (int r = 0; r < 4; r++)
                partial[((size_t)kc * S_LEN + grow + r) * 192 + gn] = acc[mt][nt][r];
        }
    }
}

__global__ __launch_bounds__(256) void kw_reduce_kernel(
    const float* __restrict__ partial, float* __restrict__ Ko, float* __restrict__ Wo)
{
    int g = blockIdx.x * 256 + threadIdx.x;   // < S*192
    int m = g / 192, n = g % 192;
    float s = 0.f;
#pragma unroll
    for (int c = 0; c < KCHUNKS; c++)
        s += partial[((size_t)c * S_LEN + m) * 192 + n];
    if (n < HD_DIM) Ko[(size_t)m * HD_DIM + n] = s;
    else            Wo[(size_t)m * H_NUM + (n - HD_DIM)] = s * W_SCALE;
}

// ---------------------------------------------------------------------------
// Kernel 3: per-row layernorm + interleaved RoPE on k; emits bf16 K.
// ---------------------------------------------------------------------------
__global__ __launch_bounds__(128) void knorm_rope_kernel(
    const float* __restrict__ Kf, const float* __restrict__ gw, const float* __restrict__ gb,
    const float* __restrict__ cosp, const float* __restrict__ sinp,
    ushort* __restrict__ Kbf)
{
    __shared__ float red[128];
    __shared__ float sh[128];
    const int m = blockIdx.x, t = threadIdx.x;
    float v = Kf[(size_t)m * HD_DIM + t];
    red[t] = v; __syncthreads();
    for (int off = 64; off > 0; off >>= 1) {
        if (t < off) red[t] += red[t + off];
        __syncthreads();
    }
    float mu = red[0] * (1.f / HD_DIM);
    __syncthreads();
    float dv = v - mu;
    red[t] = dv * dv; __syncthreads();
    for (int off = 64; off > 0; off >>= 1) {
        if (t < off) red[t] += red[t + off];
        __syncthreads();
    }
    float var = red[0] * (1.f / HD_DIM);
    float rs = rsqrtf(var + LN_EPS);
    float kn = dv * rs * gw[t] + gb[t];
    sh[t] = kn; __syncthreads();
    float out;
    if (t < ROPE_DIM) {
        int jj = t >> 1;
        float c = cosp[m * HALF_DIM + jj], sn = sinp[m * HALF_DIM + jj];
        out = ((t & 1) == 0) ? (sh[t] * c - sh[t + 1] * sn)
                             : (sh[t - 1] * sn + sh[t] * c);
    } else {
        out = kn;
    }
    Kbf[(size_t)m * HD_DIM + t] = f2bf(out);
}

// ---------------------------------------------------------------------------
// Kernel 4: index_score via bf16 MFMA, barrier-free head loop.
// ---------------------------------------------------------------------------
__global__ __launch_bounds__(256, 2) void attn_mfma_kernel(
    const ushort* __restrict__ Qb,  // bf16 frag layout [h][sgrp][ks][lane]x8
    const ushort* __restrict__ Kb,  // bf16 [S][HD]
    const float* __restrict__ Wf,   // fp32 [S][H], pre-scaled
    float* __restrict__ SC)
{
    __shared__ float Wsm[64 * 68];

    const int bidx = blockIdx.x;
    const int x = bidx & 7, j = bidx >> 3;
    const int g1 = x + 1, g2 = 32 - x, g3 = x + 9;   // group sizes (g4=24-x)
    int ts, tt;
    if (j < g1)                { ts = x;      tt = j; }
    else if (j < g1 + g2)      { ts = 31 - x; tt = j - g1; }
    else if (j < g1 + g2 + g3) { ts = x + 8;  tt = j - g1 - g2; }
    else                       { ts = 23 - x; tt = j - g1 - g2 - g3; }
    const int s0 = ts * 64, t0 = tt * 64;

    const int tid = threadIdx.x;
    const int lane = tid & 63;
    const int m = lane & 15;
    const int q = lane >> 4;
    const int strip = (tid >> 6) * 16;

    {
        const float4* gw = (const float4*)(Wf + (size_t)s0 * H_NUM);
#pragma unroll
        for (int u = 0; u < 4; u++) {
            int ch = tid + u * 256;
            float4 v = gw[ch];
            *(float4*)&Wsm[(ch >> 4) * 68 + (ch & 15) * 4] = v;
        }
    }

    short8 bf[4][4];   // [t-tile][k-step] — resident all block
#pragma unroll
    for (int tile = 0; tile < 4; tile++)
#pragma unroll
        for (int ks = 0; ks < 4; ks++)
            bf[tile][ks] = *(const short8*)
                &Kb[(size_t)(t0 + tile * 16 + m) * HD_DIM + ks * 32 + q * 8];

    __syncthreads();   // Wsm ready (only barrier)

    float acc[4][4];
#pragma unroll
    for (int tile = 0; tile < 4; tile++)
#pragma unroll
        for (int r = 0; r < 4; r++) acc[tile][r] = 0.f;

    const int sgrp = ts * 4 + (strip >> 4);
    const ushort* qfb = Qb + ((size_t)sgrp * 4 * 64 + lane) * 8;
    const float* wrow = &Wsm[(strip + q * 4) * 68];

    auto loadQ = [&](short8* dst, int h) {
        const ushort* p = qfb + (size_t)h * QF_HSTRIDE;
#pragma unroll
        for (int ks = 0; ks < 4; ks++) dst[ks] = *(const short8*)&p[ks * 512];
    };
    auto computeH = [&](const short8* af, int h) {
        float wv[4];
#pragma unroll
        for (int r = 0; r < 4; r++) wv[r] = wrow[r * 68 + h];
#pragma unroll
        for (int tile = 0; tile < 4; tile++) {
            floatx4 p = {0.f, 0.f, 0.f, 0.f};
#pragma unroll
            for (int ks = 0; ks < 4; ks++)
                p = __builtin_amdgcn_mfma_f32_16x16x32_bf16(af[ks], bf[tile][ks], p, 0, 0, 0);
#pragma unroll
            for (int r = 0; r < 4; r++)
                acc[tile][r] += fmaxf(p[r], 0.f) * wv[r];
        }
    };

    short8 afA[4], afB[4];
    loadQ(afA, 0);
    for (int h = 0; h < H_NUM; h += 2) {
        loadQ(afB, h + 1);
        computeH(afA, h);
        if (h + 2 < H_NUM) loadQ(afA, h + 2);
        computeH(afB, h + 1);
    }

#pragma unroll
    for (int tile = 0; tile < 4; tile++)
#pragma unroll
        for (int r = 0; r < 4; r++)
            SC[(size_t)(s0 + strip + q * 4 + r) * S_LEN + t0 + tile * 16 + m] =
                acc[tile][r];
}

// ---------------------------------------------------------------------------
// Kernel 5: per-row top-512, u32 compressed keys, causal-length-adaptive
// partial bitonic (chunk sorts + bitonic top-512 merges).
// ---------------------------------------------------------------------------
__device__ __forceinline__ unsigned int fkey(float f) {
    unsigned int u = __float_as_uint(f);
    return (u & 0x80000000u) ? ~u : (u | 0x80000000u);
}

__global__ __launch_bounds__(256) void topk_kernel(
    const float* __restrict__ SC, float* __restrict__ outv, float* __restrict__ outi)
{
    __shared__ unsigned int key[S_LEN];
    __shared__ float val[S_LEN];
    const int s = blockIdx.x, tid = threadIdx.x;
    const int nchunks = (s >> 9) + 1;          // 1..4 active 512-chunks
    const int nact = nchunks << 9;

    for (int t = tid; t < nact; t += 256) {
        float v = (t <= s) ? SC[(size_t)s * S_LEN + t] : NEG_INF_F;
        val[t] = v;
        key[t] = (fkey(v) & 0xFFFFF800u) | (unsigned int)(S_LEN - 1 - t);
    }
    __syncthreads();

    // Phase 1: sort each active 512-chunk descending (local-index network)
    for (int k2 = 2; k2 <= 512; k2 <<= 1) {
        for (int j = k2 >> 1; j > 0; j >>= 1) {
            for (int p = tid; p < (nact >> 1); p += 256) {
                int i = 2 * p - (p & (j - 1));
                int il = i & 511;
                unsigned int a = key[i], b = key[i + j];
                bool up = ((il & k2) == 0);
                bool sw = up ? (a < b) : (a > b);
                if (sw) { key[i] = b; key[i + j] = a; }
            }
            __syncthreads();
        }
    }

    // Phase 2: fold chunks c=1.. into chunk 0 (top-512 of union each time)
    for (int c = 1; c < nchunks; c++) {
        for (int p = tid; p < 512; p += 256) {
            unsigned int a = key[p], b = key[(c << 9) + 511 - p];
            key[p] = a > b ? a : b;    // bitonic, contains top-512
        }
        __syncthreads();
        for (int j = 256; j > 0; j >>= 1) {      // bitonic merge, descending
            int p = tid;                          // 256 pairs exactly
            int i = 2 * p - (p & (j - 1));
            unsigned int a = key[i], b = key[i + j];
            if (a < b) { key[i] = b; key[i + j] = a; }
            __syncthreads();
        }
    }

    for (int i2 = tid; i2 < TOPK_N; i2 += 256) {
        unsigned int kv = key[i2];
        int t = S_LEN - 1 - (int)(kv & 0x7FFu);
        outv[(size_t)s * TOPK_N + i2] = val[t];
        outi[(size_t)s * TOPK_N + i2] = (float)t;
    }
}

// ---------------------------------------------------------------------------
extern "C" void kernel_launch(void* const* d_in, const int* in_sizes, int n_in,
                              void* d_out, int out_size, void* d_ws, size_t ws_size,
                              hipStream_t stream)
{
    (void)in_sizes; (void)n_in; (void)out_size; (void)ws_size;
    const float* x      = (const float*)d_in[0];
    const float* q_lora = (const float*)d_in[1];
    const float* wq_b   = (const float*)d_in[2];
    const float* wk     = (const float*)d_in[3];
    const float* wproj  = (const float*)d_in[4];
    const float* knw    = (const float*)d_in[5];
    const float* knb    = (const float*)d_in[6];
    const float* cosp   = (const float*)d_in[7];
    const float* sinp   = (const float*)d_in[8];

    float* ws = (float*)d_ws;
    ushort* Qbf  = (ushort*)(ws + QBF_OFF);
    ushort* Albf = (ushort*)(ws + ALORA_OFF);
    ushort* WTbf = (ushort*)(ws + WT_OFF);
    ushort* Xbf  = (ushort*)(ws + XBF_OFF);
    ushort* WT2  = (ushort*)(ws + WT2_OFF);
    float*  Kf   = ws + KF_OFF;
    ushort* Kbf  = (ushort*)(ws + KBF_OFF);
    float*  Wf   = ws + WF_OFF;
    float*  SCb  = ws + SC_OFF;
    float*  partial = ws + SC_OFF;   // alias: consumed before SC is written

    float* outv = (float*)d_out;
    float* outi = outv + (size_t)S_LEN * TOPK_N;

    cast_bf16_kernel<<<(S_LEN * QLR_DIM) / (256 * 8), 256, 0, stream>>>(q_lora, Albf);
    cast_bf16_kernel<<<(S_LEN * D_DIM) / (256 * 8), 256, 0, stream>>>(x, Xbf);
    transpose_wqb_kernel<<<dim3(NQ_DIM / 64, QLR_DIM / 64), 256, 0, stream>>>(wq_b, WTbf);
    transpose_wkp_kernel<<<dim3(3, D_DIM / 64), 256, 0, stream>>>(wk, wproj, WT2);
    kw_mfma_kernel<<<dim3(S_LEN / 128, 3, KCHUNKS), 256, 0, stream>>>(Xbf, WT2, partial);
    kw_reduce_kernel<<<(S_LEN * 192) / 256, 256, 0, stream>>>(partial, Kf, Wf);
    knorm_rope_kernel<<<S_LEN, 128, 0, stream>>>(Kf, knw, knb, cosp, sinp, Kbf);
    qgemm_mfma_kernel<<<dim3(NQ_DIM / 128, S_LEN / 128), 256, 0, stream>>>(
        Albf, WTbf, cosp, sinp, Qbf);
    attn_mfma_kernel<<<528, 256, 0, stream>>>(Qbf, Kbf, Wf, SCb);
    topk_kernel<<<S_LEN, 256, 0, stream>>>(SCb, outv, outi);
}